// Round 16
// baseline (508.822 us; speedup 1.0000x reference)
//
#include <hip/hip_runtime.h>
#include <hip/hip_bf16.h>
#include <math.h>

#define BD   256    // D
#define NH   8      // heads
#define DH   32     // head dim
#define NB   16     // batch
#define NN   1024   // N
#define LQ   1025   // N+1
#define EPSV 1e-5f
#define KP   1088   // padded key stride for VhT (17*64)

typedef unsigned short ushort_t;
typedef __attribute__((ext_vector_type(8))) short short8;
typedef __attribute__((ext_vector_type(4))) float f32x4;

static __device__ __forceinline__ ushort_t f2b(float x) {
  union { __hip_bfloat16 h; ushort_t u; } cv;
  cv.h = __float2bfloat16(x);
  return cv.u;
}
static __device__ __forceinline__ float b2f(ushort_t u) {
  union { float f; unsigned v; } c; c.v = ((unsigned)u) << 16; return c.f;
}
static __device__ __forceinline__ float fexp2(float x) {
#if defined(__has_builtin)
#if __has_builtin(__builtin_amdgcn_exp2f)
  return __builtin_amdgcn_exp2f(x);
#else
  return exp2f(x);
#endif
#else
  return exp2f(x);
#endif
}
// full-wave (64-lane) butterfly reductions -- no barriers
static __device__ __forceinline__ float wave_sum(float x) {
  #pragma unroll
  for (int off = 1; off < 64; off <<= 1) x += __shfl_xor(x, off);
  return x;
}
static __device__ __forceinline__ float wave_max(float x) {
  #pragma unroll
  for (int off = 1; off < 64; off <<= 1) x = fmaxf(x, __shfl_xor(x, off));
  return x;
}

// ---------------- cast helper ----------------
// Pure cast: the fp32 X copy of gv is dead (layer-0 relay ops read gv directly;
// gemm_gtx2 rewrites sat rows; rowvec_oproj_ln writes relay rows from layer 0 on).
__global__ void k_copy_cast(const float* __restrict__ in,
                            ushort_t* __restrict__ Xh, long n) {
  long stride = (long)gridDim.x * 256;
  for (long i = (long)blockIdx.x * 256 + threadIdx.x; i < n; i += stride)
    Xh[i] = f2b(in[i]);
}

// ---------------- weight transpose+cast: Wt[slot][n][k] = bf16(W[k][n]) ----------------
// Q slots (type 0) are pre-scaled by C1 = 1/sqrt(dh) * log2(e) so attention scores
// come out of the MFMA already in exp2 domain.
__global__ __launch_bounds__(256) void k_wtrans(const float* __restrict__ Wq,
                                                const float* __restrict__ Wk,
                                                const float* __restrict__ Wv,
                                                const float* __restrict__ Wo,
                                                ushort_t* __restrict__ Wt) {
  const float C1 = 0.17677669529663687f * 1.4426950408889634f;
  int mat = blockIdx.y;              // 0..15: type*4 + layer
  int type = mat >> 2, layer = mat & 3;
  const float* src = (type == 0) ? Wq : (type == 1) ? Wk : (type == 2) ? Wv : Wo;
  src += (long)layer * BD * BD;
  float scv = (type == 0) ? C1 : 1.f;
  ushort_t* dst = Wt + (long)mat * BD * BD;
  __shared__ float t[32][33];
  int k0 = (blockIdx.x & 7) * 32, n0 = (blockIdx.x >> 3) * 32;
  int tid = threadIdx.x;
  for (int i = tid; i < 1024; i += 256) {
    int kk = i >> 5, nn = i & 31;
    t[kk][nn] = src[(long)(k0 + kk) * BD + n0 + nn];
  }
  __syncthreads();
  for (int i = tid; i < 1024; i += 256) {
    int nn = i >> 5, kk = i & 31;
    dst[(long)(n0 + nn) * BD + k0 + kk] = f2b(t[kk][nn] * scv);
  }
}

// ---------------- G transpose+cast: Ght[b][m][n] = bf16(G[b][n][m]) ----------------
__global__ __launch_bounds__(256) void k_gtrans(const float* __restrict__ G,
                                                ushort_t* __restrict__ Ght) {
  __shared__ ushort_t t[64][65];
  int b = blockIdx.y;
  int m0 = (blockIdx.x & 15) * 64, n0 = (blockIdx.x >> 4) * 64;
  const float* Gb = G + (long)b * NN * NN;
  ushort_t* dst = Ght + (long)b * NN * NN;
  int tid = threadIdx.x;
  #pragma unroll
  for (int rr = 0; rr < 16; rr++) {
    int n = rr * 4 + (tid >> 6);
    int m = tid & 63;
    t[m][n] = f2b(Gb[(long)(n0 + n) * NN + m0 + m]);
  }
  __syncthreads();
  #pragma unroll
  for (int rr = 0; rr < 8; rr++) {
    int m = rr * 8 + (tid >> 5);
    int n2 = (tid & 31) * 2;
    unsigned w = (unsigned)t[m][n2] | ((unsigned)t[m][n2 + 1] << 16);
    *(unsigned*)&dst[(long)(m0 + m) * NN + n0 + n2] = w;
  }
}

// ---------------- sat transpose: satT[b][d][n] = Xh_sat[b][n][d] ----------------
__global__ __launch_bounds__(256) void k_satT(const ushort_t* __restrict__ Xh,
                                              ushort_t* __restrict__ satT) {
  __shared__ ushort_t t[64][65];
  int b = blockIdx.y;
  int n0 = (blockIdx.x & 15) * 64, d0 = (blockIdx.x >> 4) * 64;
  const ushort_t* src = Xh + ((long)b * LQ + 1) * BD;
  ushort_t* dst = satT + (long)b * BD * NN;
  int tid = threadIdx.x;
  #pragma unroll
  for (int rr = 0; rr < 16; rr++) {
    int n = rr * 4 + (tid >> 6);
    int d = tid & 63;
    t[n][d] = src[(long)(n0 + n) * BD + d0 + d];
  }
  __syncthreads();
  #pragma unroll
  for (int rr = 0; rr < 8; rr++) {
    int d = rr * 8 + (tid >> 5);
    int n2 = (tid & 31) * 2;
    unsigned w = (unsigned)t[n2][d] | ((unsigned)t[n2 + 1][d] << 16);
    *(unsigned*)&dst[(long)(d0 + d) * NN + n0 + n2] = w;
  }
}

// ---------------- VhT pad zero: cols LQ..KP-1 must be 0 (corrupted by aliased B1) ----
__global__ __launch_bounds__(256) void k_vpad(ushort_t* __restrict__ VhT) {
  int b = blockIdx.x, d = threadIdx.x;
  ushort_t* row = VhT + (long)b * BD * KP + (long)d * KP + LQ;
  #pragma unroll
  for (int k = 0; k < KP - LQ; k++) row[k] = 0;
}

// ---------------- 128x128 LDS-staged GEMM core (A[M,256] @ W[256(n),256(k)]^T) ----------------
// Async-stage (T14): issue next k-tile global loads to regs, compute current from LDS,
// barrier, ds_write, barrier. 4 waves each own a 64x64 quadrant (4x4 fragments,
// 16 MFMA/k-step). LDS pitch 72 shorts (144B). K=256 in 8 steps of 32.
// NOTE (R11 lesson): do NOT add a residual-read to this epilogue -- moving the
// coalesced ln_residual X-read into scattered per-fragment loads cost 35 us.
static __device__ __forceinline__ void core128(const ushort_t* __restrict__ A,
                                               const ushort_t* __restrict__ W,
                                               ushort_t* As, ushort_t* Bs,
                                               int M, int m0, int n0,
                                               float* __restrict__ Cf,
                                               ushort_t* __restrict__ Ch) {
  int tid = threadIdx.x;
  int wave = tid >> 6, lane = tid & 63;
  int l15 = lane & 15, quad = lane >> 4;
  int wr = wave >> 1, wc = wave & 1;

  int sr = tid >> 2, sc = (tid & 3) * 8;
  int ar0 = m0 + sr;      if (ar0 > M - 1) ar0 = M - 1;
  int ar1 = m0 + sr + 64; if (ar1 > M - 1) ar1 = M - 1;
  const ushort_t* aSrc0 = A + (long)ar0 * 256 + sc;
  const ushort_t* aSrc1 = A + (long)ar1 * 256 + sc;
  const ushort_t* bSrc0 = W + (long)(n0 + sr) * 256 + sc;
  const ushort_t* bSrc1 = bSrc0 + 64 * 256;
  ushort_t* aDst0 = &As[sr * 72 + sc];
  ushort_t* aDst1 = aDst0 + 64 * 72;
  ushort_t* bDst0 = &Bs[sr * 72 + sc];
  ushort_t* bDst1 = bDst0 + 64 * 72;

  {
    uint4 a0 = *(const uint4*)aSrc0;
    uint4 a1 = *(const uint4*)aSrc1;
    uint4 b0 = *(const uint4*)bSrc0;
    uint4 b1 = *(const uint4*)bSrc1;
    *(uint4*)aDst0 = a0; *(uint4*)aDst1 = a1;
    *(uint4*)bDst0 = b0; *(uint4*)bDst1 = b1;
  }
  __syncthreads();

  f32x4 acc[4][4];
  #pragma unroll
  for (int i = 0; i < 4; i++)
    #pragma unroll
    for (int j = 0; j < 4; j++) { acc[i][j][0] = 0.f; acc[i][j][1] = 0.f; acc[i][j][2] = 0.f; acc[i][j][3] = 0.f; }

  for (int ks = 0; ks < 8; ks++) {
    bool more = (ks < 7);
    uint4 na0, na1, nb0, nb1;
    if (more) {
      aSrc0 += 32; aSrc1 += 32; bSrc0 += 32; bSrc1 += 32;
      na0 = *(const uint4*)aSrc0;
      na1 = *(const uint4*)aSrc1;
      nb0 = *(const uint4*)bSrc0;
      nb1 = *(const uint4*)bSrc1;
    }
    short8 af[4], bf[4];
    #pragma unroll
    for (int f = 0; f < 4; f++)
      af[f] = *(const short8*)&As[(wr * 64 + f * 16 + l15) * 72 + quad * 8];
    #pragma unroll
    for (int f = 0; f < 4; f++)
      bf[f] = *(const short8*)&Bs[(wc * 64 + f * 16 + l15) * 72 + quad * 8];
    #pragma unroll
    for (int i = 0; i < 4; i++)
      #pragma unroll
      for (int j = 0; j < 4; j++)
        acc[i][j] = __builtin_amdgcn_mfma_f32_16x16x32_bf16(af[i], bf[j], acc[i][j], 0, 0, 0);
    if (more) {
      __syncthreads();
      *(uint4*)aDst0 = na0;
      *(uint4*)aDst1 = na1;
      *(uint4*)bDst0 = nb0;
      *(uint4*)bDst1 = nb1;
      __syncthreads();
    }
  }

  #pragma unroll
  for (int i = 0; i < 4; i++)
    #pragma unroll
    for (int j = 0; j < 4; j++)
      #pragma unroll
      for (int r = 0; r < 4; r++) {
        int m = m0 + wr * 64 + i * 16 + quad * 4 + r;
        if (m < M) {
          long idx = (long)m * 256 + n0 + wc * 64 + j * 16 + l15;
          if (Cf) Cf[idx] = acc[i][j][r];
          else    Ch[idx] = f2b(acc[i][j][r]);
        }
      }
}

// fused Q/K projection: grid (129, 4) ; blockIdx.y = which*2 + n-tile (which: 0=Q, 1=K)
__global__ __launch_bounds__(256) void gemm_qkv(const ushort_t* __restrict__ Xh,
                                                const ushort_t* __restrict__ Wt, int layer,
                                                ushort_t* __restrict__ Qo,
                                                ushort_t* __restrict__ Ko, int M) {
  __shared__ __align__(16) ushort_t As[128 * 72];
  __shared__ __align__(16) ushort_t Bs[128 * 72];
  int which = blockIdx.y >> 1;
  int n0 = (blockIdx.y & 1) * 128;
  const ushort_t* W = Wt + (long)(which * 4 + layer) * 65536;
  ushort_t* C = (which == 0) ? Qo : Ko;
  core128(Xh, W, As, Bs, M, blockIdx.x * 128, n0, nullptr, C);
}

// V projection with FUSED transposed write (deletes k_vtrans): grid (129, 2).
// Same staging/k-loop as core128 (duplicated so core128 users keep their codegen);
// epilogue stages the C-tile into the now-dead As/Bs LDS ([m][130] pitch) and then
// writes VhT[b][d][key] with 64-consecutive-key coalesced stores (k_vtrans pattern).
__global__ __launch_bounds__(256) void gemm_vT(const ushort_t* __restrict__ Xh,
                                               const ushort_t* __restrict__ Wt, int layer,
                                               ushort_t* __restrict__ VhT, int M) {
  __shared__ __align__(16) char smem[36864];     // max(2*128*72*2, 128*130*2)
  ushort_t* As = (ushort_t*)smem;
  ushort_t* Bs = As + 128 * 72;
  ushort_t* Ls = (ushort_t*)smem;                // reused after k-loop
  const ushort_t* W = Wt + (long)(8 + layer) * 65536;
  int tid = threadIdx.x;
  int wave = tid >> 6, lane = tid & 63;
  int l15 = lane & 15, quad = lane >> 4;
  int wr = wave >> 1, wc = wave & 1;
  int m0 = blockIdx.x * 128, n0 = blockIdx.y * 128;

  int sr = tid >> 2, sc = (tid & 3) * 8;
  int ar0 = m0 + sr;      if (ar0 > M - 1) ar0 = M - 1;
  int ar1 = m0 + sr + 64; if (ar1 > M - 1) ar1 = M - 1;
  const ushort_t* aSrc0 = Xh + (long)ar0 * 256 + sc;
  const ushort_t* aSrc1 = Xh + (long)ar1 * 256 + sc;
  const ushort_t* bSrc0 = W + (long)(n0 + sr) * 256 + sc;
  const ushort_t* bSrc1 = bSrc0 + 64 * 256;
  ushort_t* aDst0 = &As[sr * 72 + sc];
  ushort_t* aDst1 = aDst0 + 64 * 72;
  ushort_t* bDst0 = &Bs[sr * 72 + sc];
  ushort_t* bDst1 = bDst0 + 64 * 72;

  {
    uint4 a0 = *(const uint4*)aSrc0;
    uint4 a1 = *(const uint4*)aSrc1;
    uint4 b0 = *(const uint4*)bSrc0;
    uint4 b1 = *(const uint4*)bSrc1;
    *(uint4*)aDst0 = a0; *(uint4*)aDst1 = a1;
    *(uint4*)bDst0 = b0; *(uint4*)bDst1 = b1;
  }
  __syncthreads();

  f32x4 acc[4][4];
  #pragma unroll
  for (int i = 0; i < 4; i++)
    #pragma unroll
    for (int j = 0; j < 4; j++) { acc[i][j][0] = 0.f; acc[i][j][1] = 0.f; acc[i][j][2] = 0.f; acc[i][j][3] = 0.f; }

  for (int ks = 0; ks < 8; ks++) {
    bool more = (ks < 7);
    uint4 na0, na1, nb0, nb1;
    if (more) {
      aSrc0 += 32; aSrc1 += 32; bSrc0 += 32; bSrc1 += 32;
      na0 = *(const uint4*)aSrc0;
      na1 = *(const uint4*)aSrc1;
      nb0 = *(const uint4*)bSrc0;
      nb1 = *(const uint4*)bSrc1;
    }
    short8 af[4], bf[4];
    #pragma unroll
    for (int f = 0; f < 4; f++)
      af[f] = *(const short8*)&As[(wr * 64 + f * 16 + l15) * 72 + quad * 8];
    #pragma unroll
    for (int f = 0; f < 4; f++)
      bf[f] = *(const short8*)&Bs[(wc * 64 + f * 16 + l15) * 72 + quad * 8];
    #pragma unroll
    for (int i = 0; i < 4; i++)
      #pragma unroll
      for (int j = 0; j < 4; j++)
        acc[i][j] = __builtin_amdgcn_mfma_f32_16x16x32_bf16(af[i], bf[j], acc[i][j], 0, 0, 0);
    if (more) {
      __syncthreads();
      *(uint4*)aDst0 = na0;
      *(uint4*)aDst1 = na1;
      *(uint4*)bDst0 = nb0;
      *(uint4*)bDst1 = nb1;
      __syncthreads();
    }
  }

  // ---- transposed epilogue ----
  __syncthreads();             // all As/Bs reads complete before Ls reuse
  #pragma unroll
  for (int i = 0; i < 4; i++)
    #pragma unroll
    for (int j = 0; j < 4; j++)
      #pragma unroll
      for (int r = 0; r < 4; r++) {
        int ml = wr * 64 + i * 16 + quad * 4 + r;
        int nl = wc * 64 + j * 16 + l15;
        Ls[ml * 130 + nl] = f2b(acc[i][j][r]);
      }
  __syncthreads();
  // at most one batch boundary inside this 128-row m-range
  int b_lo = m0 / LQ;
  int m_sw = (b_lo + 1) * LQ;
  for (int rr = 0; rr < 64; rr++) {
    int idx = rr * 256 + tid;
    int n = idx >> 7, kk = idx & 127;
    int mg = m0 + kk;
    if (mg < M) {
      int bb = (mg >= m_sw) ? (b_lo + 1) : b_lo;
      int key = mg - bb * LQ;
      VhT[(long)bb * BD * KP + (long)(n0 + n) * KP + key] = Ls[kk * 130 + n];
    }
  }
}

// fused relay K/V projection over sat rows: grid (8, 4, NB); y = which*2 + n-tile
__global__ __launch_bounds__(256) void gemm_kv(const ushort_t* __restrict__ Xh,
                                               const ushort_t* __restrict__ Wt, int layer,
                                               ushort_t* __restrict__ Ko,
                                               ushort_t* __restrict__ Vo) {
  __shared__ __align__(16) ushort_t As[128 * 72];
  __shared__ __align__(16) ushort_t Bs[128 * 72];
  int which = blockIdx.y >> 1;
  int n0 = (blockIdx.y & 1) * 128;
  int b = blockIdx.z;
  const ushort_t* W = Wt + (long)((which + 1) * 4 + layer) * 65536;
  const ushort_t* A = Xh + (long)b * (LQ * BD) + BD;
  ushort_t* C = ((which == 0) ? Ko : Vo) + (long)b * (NN * BD);
  core128(A, W, As, Bs, NN, blockIdx.x * 128, n0, nullptr, C);
}

// o-projection, fp32 out: grid (129, 2)
__global__ __launch_bounds__(256) void gemm_oproj(const ushort_t* __restrict__ Oh,
                                                  const ushort_t* __restrict__ Wt, int layer,
                                                  float* __restrict__ Cf, int M) {
  __shared__ __align__(16) ushort_t As[128 * 72];
  __shared__ __align__(16) ushort_t Bs[128 * 72];
  core128(Oh, Wt + (long)(12 + layer) * 65536, As, Bs, M,
          blockIdx.x * 128, blockIdx.y * 128, Cf, nullptr);
}

// ---------------- graph mixing: X_sat[b,m,d] = sum_n Ght[b,m,n] * satT[b,d,n] ----------------
// LDS-staged tiled GEMM, async-stage (T14). Tile BM=128 x BN=128, 4 waves each 64x64.
// LDS pitch 72 shorts (144B). grid (8, 2, NB) = 256 blocks = 1 block/CU.
__global__ __launch_bounds__(256) void gemm_gtx2(const ushort_t* __restrict__ Ght,
                                                 const ushort_t* __restrict__ satT,
                                                 float* __restrict__ X,
                                                 ushort_t* __restrict__ Xh) {
  __shared__ __align__(16) ushort_t As[128 * 72];
  __shared__ __align__(16) ushort_t Bs[128 * 72];
  int b = blockIdx.z;
  const ushort_t* A  = Ght + (long)b * NN * NN;    // [1024][1024]
  const ushort_t* Bp = satT + (long)b * BD * NN;   // [256][1024]
  int tid = threadIdx.x;
  int wave = tid >> 6, lane = tid & 63;
  int l15 = lane & 15, quad = lane >> 4;
  int wr = wave >> 1, wc = wave & 1;
  int m0 = blockIdx.x * 128, d0 = blockIdx.y * 128;

  int sr = tid >> 2, sc = (tid & 3) * 8;
  const ushort_t* aSrc0 = A  + (long)(m0 + sr) * NN + sc;
  const ushort_t* aSrc1 = aSrc0 + (long)64 * NN;
  const ushort_t* bSrc0 = Bp + (long)(d0 + sr) * NN + sc;
  const ushort_t* bSrc1 = bSrc0 + (long)64 * NN;
  ushort_t* aDst0 = &As[sr * 72 + sc];
  ushort_t* aDst1 = aDst0 + 64 * 72;
  ushort_t* bDst0 = &Bs[sr * 72 + sc];
  ushort_t* bDst1 = bDst0 + 64 * 72;

  {
    uint4 a0 = *(const uint4*)aSrc0;
    uint4 a1 = *(const uint4*)aSrc1;
    uint4 b0 = *(const uint4*)bSrc0;
    uint4 b1 = *(const uint4*)bSrc1;
    *(uint4*)aDst0 = a0; *(uint4*)aDst1 = a1;
    *(uint4*)bDst0 = b0; *(uint4*)bDst1 = b1;
  }
  __syncthreads();

  f32x4 acc[4][4];
  #pragma unroll
  for (int i = 0; i < 4; i++)
    #pragma unroll
    for (int j = 0; j < 4; j++) { acc[i][j][0] = 0.f; acc[i][j][1] = 0.f; acc[i][j][2] = 0.f; acc[i][j][3] = 0.f; }

  for (int ks = 0; ks < 32; ks++) {
    bool more = (ks < 31);
    uint4 na0, na1, nb0, nb1;
    if (more) {
      aSrc0 += 32; aSrc1 += 32; bSrc0 += 32; bSrc1 += 32;
      na0 = *(const uint4*)aSrc0;
      na1 = *(const uint4*)aSrc1;
      nb0 = *(const uint4*)bSrc0;
      nb1 = *(const uint4*)bSrc1;
    }
    short8 af[4], bf[4];
    #pragma unroll
    for (int f = 0; f < 4; f++)
      af[f] = *(const short8*)&As[(wr * 64 + f * 16 + l15) * 72 + quad * 8];
    #pragma unroll
    for (int f = 0; f < 4; f++)
      bf[f] = *(const short8*)&Bs[(wc * 64 + f * 16 + l15) * 72 + quad * 8];
    #pragma unroll
    for (int i = 0; i < 4; i++)
      #pragma unroll
      for (int j = 0; j < 4; j++)
        acc[i][j] = __builtin_amdgcn_mfma_f32_16x16x32_bf16(af[i], bf[j], acc[i][j], 0, 0, 0);
    if (more) {
      __syncthreads();
      *(uint4*)aDst0 = na0;
      *(uint4*)aDst1 = na1;
      *(uint4*)bDst0 = nb0;
      *(uint4*)bDst1 = nb1;
      __syncthreads();
    }
  }

  long xb = ((long)b * LQ + 1) * 256;
  #pragma unroll
  for (int i = 0; i < 4; i++)
    #pragma unroll
    for (int j = 0; j < 4; j++)
      #pragma unroll
      for (int r = 0; r < 4; r++) {
        int m = m0 + wr * 64 + i * 16 + quad * 4 + r;
        int d = d0 + wc * 64 + j * 16 + l15;
        long idx = xb + (long)m * 256 + d;
        X[idx] = acc[i][j][r];
        Xh[idx] = f2b(acc[i][j][r]);
      }
}

// ---------------- attention: single-pass online softmax (deferred rescale) ----------------
// R9-measured version verbatim (67.7 us, 7x-reproduced): single-buffered K/V,
// scalar ls + Lbuf publish + f2b P-packing + balanced pairwise chunk-max tree.
// Rejected variants (ALL measured): MFMA row-sum denominator (R3, 72.5us); inline-asm
// cvt_pk (R6, WRONG on gfx950); max3-style 3-way max nests (R7, 74.9us, serial dep
// chain); K/V double-buffer + packed convert (R10, 70.0us, occupancy 29->24%);
// residual-fused oproj epilogue (R11, +35us total, scattered epilogue loads).
// grid (NB*NH, 9); block 256 = 4 waves, 32 q/wave. Q pre-scaled by C1 (in Wt).
// Online max required (layer-1 scores reach +-150 in exp2 domain). Deferred rescale
// (threshold 8 -> p <= 2^8). K/V chunks staged in LDS, reg-staged (T14).
__global__ __launch_bounds__(256) void attn_fa(const ushort_t* __restrict__ Qh,
                                               const ushort_t* __restrict__ Kh,
                                               const ushort_t* __restrict__ VhT,
                                               ushort_t* __restrict__ Oh) {
  __shared__ __align__(16) ushort_t Ps[4][32][72];
  __shared__ __align__(16) ushort_t Kb[64 * 72];   // pitch 72 (144B = 9*16B)
  __shared__ __align__(16) ushort_t Vb[32 * 72];
  __shared__ float Lbuf[4][32];
  int tid = threadIdx.x;
  int wave = tid >> 6, lane = tid & 63;
  int l15 = lane & 15, quad = lane >> 4;
  int b = blockIdx.x >> 3, h = blockIdx.x & 7;
  long hb = ((long)b * LQ) * BD + h * DH;
  long vB = (long)b * BD * KP;
  int hd0 = h * DH;
  int q0 = blockIdx.y * 128 + wave * 32;
  int lq = lane & 48;

  short8 qB[2];
  #pragma unroll
  for (int t = 0; t < 2; t++) {
    int qc = q0 + t * 16 + l15; if (qc > LQ - 1) qc = LQ - 1;
    qB[t] = *(const short8*)&Qh[hb + (long)qc * BD + quad * 8];
  }

  // per-wave staging assignment: 2 segments of 1KB each
  const ushort_t *s0, *s1;
  ushort_t *d0, *d1;
  long stp;
  if (wave < 2) {
    int kt0 = wave * 2, kt1 = kt0 + 1;
    s0 = Kh + hb + (long)(kt0 * 16 + l15) * BD + quad * 8;
    s1 = Kh + hb + (long)(kt1 * 16 + l15) * BD + quad * 8;
    d0 = &Kb[(kt0 * 16 + l15) * 72 + quad * 8];
    d1 = &Kb[(kt1 * 16 + l15) * 72 + quad * 8];
    stp = (long)64 * BD;
  } else {
    int sa = (wave - 2) * 2, sb = sa + 1;   // dt = s>>1, ks = s&1
    s0 = VhT + vB + (long)(hd0 + (sa >> 1) * 16 + l15) * KP + (sa & 1) * 32 + quad * 8;
    s1 = VhT + vB + (long)(hd0 + (sb >> 1) * 16 + l15) * KP + (sb & 1) * 32 + quad * 8;
    d0 = &Vb[((sa >> 1) * 16 + l15) * 72 + (sa & 1) * 32 + quad * 8];
    d1 = &Vb[((sb >> 1) * 16 + l15) * 72 + (sb & 1) * 32 + quad * 8];
    stp = 64;
  }
  {
    uint4 r0 = *(const uint4*)s0;
    uint4 r1 = *(const uint4*)s1;
    *(uint4*)d0 = r0;
    *(uint4*)d1 = r1;
  }
  __syncthreads();

  f32x4 o[2][2];
  #pragma unroll
  for (int t = 0; t < 2; t++)
    #pragma unroll
    for (int dt = 0; dt < 2; dt++) { o[t][dt][0] = 0.f; o[t][dt][1] = 0.f; o[t][dt][2] = 0.f; o[t][dt][3] = 0.f; }
  float m[2] = {-1e30f, -1e30f};
  float ls[2] = {0.f, 0.f};
  f32x4 zf; zf[0] = 0.f; zf[1] = 0.f; zf[2] = 0.f; zf[3] = 0.f;

  for (int c = 0; c < 17; c++) {
    bool more = (c < 16);
    uint4 n0, n1;
    if (more) {
      if (c == 15 && wave < 2) {
        // chunk 16 K rows (1024..1087) all clamp to row 1024; masked in compute
        const ushort_t* cl = Kh + hb + (long)(LQ - 1) * BD + quad * 8;
        n0 = *(const uint4*)cl;
        n1 = n0;
      } else {
        s0 += stp; s1 += stp;
        n0 = *(const uint4*)s0;
        n1 = *(const uint4*)s1;
      }
    }
    short8 ka[4];
    #pragma unroll
    for (int kt = 0; kt < 4; kt++)
      ka[kt] = *(const short8*)&Kb[(kt * 16 + l15) * 72 + quad * 8];

    bool tail = (c == 16);
    #pragma unroll
    for (int t = 0; t < 2; t++) {
      f32x4 s[4];
      #pragma unroll
      for (int kt = 0; kt < 4; kt++)
        s[kt] = __builtin_amdgcn_mfma_f32_16x16x32_bf16(ka[kt], qB[t], zf, 0, 0, 0);
      if (tail) {
        // only key 1024 (kt=0, quad=0, r=0) is valid; mask the rest
        #pragma unroll
        for (int kt = 0; kt < 4; kt++)
          #pragma unroll
          for (int r = 0; r < 4; r++)
            if (kt + r) s[kt][r] = -1e30f;
        if (quad) s[0][0] = -1e30f;
      }
      // chunk row-max (balanced pairwise tree -- max ILP; scores already in exp2 domain)
      float cm = fmaxf(fmaxf(s[0][0], s[0][1]), fmaxf(s[0][2], s[0][3]));
      cm = fmaxf(cm, fmaxf(fmaxf(s[1][0], s[1][1]), fmaxf(s[1][2], s[1][3])));
      cm = fmaxf(cm, fmaxf(fmaxf(s[2][0], s[2][1]), fmaxf(s[2][2], s[2][3])));
      cm = fmaxf(cm, fmaxf(fmaxf(s[3][0], s[3][1]), fmaxf(s[3][2], s[3][3])));
      cm = fmaxf(cm, __shfl_xor(cm, 16));
      cm = fmaxf(cm, __shfl_xor(cm, 32));
      if (__any(cm > m[t] + 8.f)) {
        float mn = fmaxf(m[t], cm);
        float f = fexp2(m[t] - mn);
        ls[t] *= f;
        m[t] = mn;
        #pragma unroll
        for (int r = 0; r < 4; r++) {
          // o-row q = quad*4+r lives at lane l15 = quad*4+r (same quad group)
          float fr = __shfl(f, lq | (quad * 4 + r));
          o[t][0][r] *= fr;
          o[t][1][r] *= fr;
        }
      }
      float mt = m[t];
      #pragma unroll
      for (int kt = 0; kt < 4; kt++) {
        float p0 = fexp2(s[kt][0] - mt);
        float p1 = fexp2(s[kt][1] - mt);
        float p2 = fexp2(s[kt][2] - mt);
        float p3 = fexp2(s[kt][3] - mt);
        ls[t] += (p0 + p1) + (p2 + p3);
        unsigned lo = (unsigned)f2b(p0) | ((unsigned)f2b(p1) << 16);
        unsigned hi = (unsigned)f2b(p2) | ((unsigned)f2b(p3) << 16);
        uint2 w; w.x = lo; w.y = hi;
        *(uint2*)&Ps[wave][t * 16 + l15][kt * 16 + quad * 4] = w;
      }
    }
    // PV: o[q][d] += P[q][keys] * V[keys][d]  (Ps wave-private)
    short8 vb[2][2];
    #pragma unroll
    for (int dt = 0; dt < 2; dt++)
      #pragma unroll
      for (int ks = 0; ks < 2; ks++)
        vb[ks][dt] = *(const short8*)&Vb[(dt * 16 + l15) * 72 + ks * 32 + quad * 8];
    #pragma unroll
    for (int ks = 0; ks < 2; ks++) {
      short8 pa0 = *(const short8*)&Ps[wave][l15][ks * 32 + quad * 8];
      short8 pa1 = *(const short8*)&Ps[wave][16 + l15][ks * 32 + quad * 8];
      #pragma unroll
      for (int dt = 0; dt < 2; dt++) {
        o[0][dt] = __builtin_amdgcn_mfma_f32_16x16x32_bf16(pa0, vb[ks][dt], o[0][dt], 0, 0, 0);
        o[1][dt] = __builtin_amdgcn_mfma_f32_16x16x32_bf16(pa1, vb[ks][dt], o[1][dt], 0, 0, 0);
      }
    }
    if (more) {
      __syncthreads();           // everyone done reading Kb/Vb
      *(uint4*)d0 = n0;          // waits vmcnt via reg dependency
      *(uint4*)d1 = n1;
      __syncthreads();           // chunk c+1 staged
    }
  }
  // denominator: reduce quad-copies, publish via LDS with a full barrier
  #pragma unroll
  for (int t = 0; t < 2; t++) {
    ls[t] += __shfl_xor(ls[t], 16);
    ls[t] += __shfl_xor(ls[t], 32);
  }
  if (quad == 0) {
    Lbuf[wave][l15] = ls[0];
    Lbuf[wave][16 + l15] = ls[1];
  }
  __syncthreads();
  #pragma unroll
  for (int mt = 0; mt < 2; mt++) {
    f32x4 lv = *(const f32x4*)&Lbuf[wave][mt * 16 + quad * 4];
    #pragma unroll
    for (int r = 0; r < 4; r++) {
      int row = q0 + mt * 16 + quad * 4 + r;
      if (row < LQ) {
        float den = lv[r];
        float inv = (den > 0.f) ? 1.f / den : 0.f;
        #pragma unroll
        for (int dt = 0; dt < 2; dt++)
          Oh[hb + (long)row * BD + dt * 16 + l15] = f2b(o[mt][dt][r] * inv);
      }
    }
  }
}

// ---------------- relay attention: Lq=1, Lk=1024, bf16 K/V ----------------
// Barrier-light (R13) + fused q-projection (R15): each (b,h) block computes its
// own 32-wide q slice directly. X may be gv (layer 0) -- same row stride.
__global__ __launch_bounds__(256) void attn_relay(const float* __restrict__ X, long xstride,
                                                  const float* __restrict__ Wq,
                                                  const ushort_t* __restrict__ K,
                                                  const ushort_t* __restrict__ V,
                                                  float* __restrict__ o) {
  int b = blockIdx.x, h = blockIdx.y;
  int tid = threadIdx.x;
  int wave = tid >> 6, lane = tid & 63;
  const float scale = 0.17677669529663687f;
  __shared__ float s[NN];
  __shared__ float xs[BD];
  __shared__ float qs[DH];
  __shared__ float pmax[4], psum[4];
  __shared__ float part[8][33];
  // --- fused q projection: qs[d] = X[b] . Wq[:, h*DH + d] ---
  xs[tid] = X[(long)b * xstride + tid];
  __syncthreads();
  {
    int d = tid & 31, slice = tid >> 5;
    const float* wq = Wq + h * DH + d;
    float partial = 0.f;
    #pragma unroll
    for (int kk = 0; kk < 32; kk++) {
      int k = slice * 32 + kk;
      partial += xs[k] * wq[(long)k * BD];
    }
    part[slice][d] = partial;
  }
  __syncthreads();
  if (tid < DH) {
    float ss = 0.f;
    #pragma unroll
    for (int t = 0; t < 8; t++) ss += part[t][tid];
    qs[tid] = ss;
  }
  __syncthreads();
  // --- scores ---
  long base = ((long)b * NN) * BD + h * DH;
  float lm = -1e30f;
  for (int k = tid; k < NN; k += 256) {
    float dot = 0.f;
    const ushort_t* kr = &K[base + (long)k * BD];
    #pragma unroll
    for (int d2 = 0; d2 < 16; d2++) {
      unsigned w = *(const unsigned*)&kr[d2 * 2];
      dot += qs[d2 * 2] * b2f((ushort_t)(w & 0xffff)) + qs[d2 * 2 + 1] * b2f((ushort_t)(w >> 16));
    }
    float sv = dot * scale;
    s[k] = sv;
    lm = fmaxf(lm, sv);
  }
  lm = wave_max(lm);
  if (lane == 0) pmax[wave] = lm;
  __syncthreads();          // s[] visible + pmax visible
  float mx = fmaxf(fmaxf(pmax[0], pmax[1]), fmaxf(pmax[2], pmax[3]));
  float sm = 0.f;
  for (int k = tid; k < NN; k += 256) {
    float p = __expf(s[k] - mx);
    s[k] = p;
    sm += p;
  }
  sm = wave_sum(sm);
  if (lane == 0) psum[wave] = sm;
  __syncthreads();          // exp'd s[] visible + psum visible
  float inv = 1.f / (((psum[0] + psum[1]) + (psum[2] + psum[3])));
  int d = tid & 31, slice = tid >> 5;
  float acc = 0.f;
  for (int k = slice; k < NN; k += 8) acc += s[k] * b2f(V[base + (long)k * BD + d]);
  part[slice][d] = acc;
  __syncthreads();
  if (tid < DH) {
    float ss = 0.f;
    #pragma unroll
    for (int t = 0; t < 8; t++) ss += part[t][tid];
    o[(long)b * BD + h * DH + tid] = ss * inv;
  }
}

// ---------------- relay row ops (fp32 weights; tiny) ----------------
__global__ __launch_bounds__(256) void rowvec_oproj_ln(const float* __restrict__ o,
                                                       const float* __restrict__ Wo,
                                                       const float* __restrict__ Xres, long xstride,
                                                       const float* __restrict__ g,
                                                       const float* __restrict__ beta,
                                                       float* __restrict__ dst, long dstride,
                                                       ushort_t* __restrict__ dsth, long dhstride) {
  int b = blockIdx.x, tid = threadIdx.x;
  int wave = tid >> 6, lane = tid & 63;
  __shared__ float xs[BD];
  __shared__ float ps[4], pq[4];
  xs[tid] = o[(long)b * BD + tid];
  __syncthreads();
  float acc = 0.f;
  for (int k = 0; k < BD; k++) acc += xs[k] * Wo[(long)k * BD + tid];
  float v = acc + Xres[(long)b * xstride + tid];
  float sum = wave_sum(v);
  float sq  = wave_sum(v * v);
  if (lane == 0) { ps[wave] = sum; pq[wave] = sq; }
  __syncthreads();
  float ts = (ps[0] + ps[1]) + (ps[2] + ps[3]);
  float tq = (pq[0] + pq[1]) + (pq[2] + pq[3]);
  float mu = ts * (1.f / BD);
  float var = tq * (1.f / BD) - mu * mu;
  float y = (v - mu) * rsqrtf(var + EPSV) * g[tid] + beta[tid];
  dst[(long)b * dstride + tid] = y;
  if (dsth) dsth[(long)b * dhstride + tid] = f2b(y);
}

// ln_residual with optional fused sat-output store (replaces k_sat_out at layer 2):
// sat_out[b][r-1][:] = y for sat rows r>=1. Wave-shfl reduction: 1 barrier (was 9).
// When sat_out is set (layer 2), X sat-row writes are DEAD (only relay rows of X
// are read after layer 2; sat output flows through sat_out) -- skip them.
__global__ __launch_bounds__(256) void ln_residual(const float* __restrict__ OP,
                                                   float* __restrict__ X,
                                                   ushort_t* __restrict__ Xh,
                                                   const float* __restrict__ g,
                                                   const float* __restrict__ beta,
                                                   float* __restrict__ sat_out) {
  long r = blockIdx.x;
  int tid = threadIdx.x;
  int wave = tid >> 6, lane = tid & 63;
  __shared__ float ps[4], pq[4];
  float v = OP[r * BD + tid] + X[r * BD + tid];
  float sum = wave_sum(v);
  float sq  = wave_sum(v * v);
  if (lane == 0) { ps[wave] = sum; pq[wave] = sq; }
  __syncthreads();
  float ts = (ps[0] + ps[1]) + (ps[2] + ps[3]);
  float tq = (pq[0] + pq[1]) + (pq[2] + pq[3]);
  float mu = ts * (1.f / BD);
  float var = tq * (1.f / BD) - mu * mu;
  float y = (v - mu) * rsqrtf(var + EPSV) * g[tid] + beta[tid];
  Xh[r * BD + tid] = f2b(y);
  if (sat_out) {
    long b = r / LQ;
    long rr = r - b * LQ;
    if (rr > 0)
      sat_out[(b * (long)NN + (rr - 1)) * BD + tid] = y;
    else
      X[r * BD + tid] = y;       // relay row still needed by layer 3
  } else {
    X[r * BD + tid] = y;
  }
}

// ---------------- launch ----------------
extern "C" void kernel_launch(void* const* d_in, const int* in_sizes, int n_in,
                              void* d_out, int out_size, void* d_ws, size_t ws_size,
                              hipStream_t stream) {
  const float* gv    = (const float*)d_in[0];
  const float* graph = (const float*)d_in[1];
  const float* Wq    = (const float*)d_in[2];
  const float* Wk    = (const float*)d_in[3];
  const float* Wv    = (const float*)d_in[4];
  const float* Wo    = (const float*)d_in[5];
  const float* lg    = (const float*)d_in[6];
  const float* lb    = (const float*)d_in[7];
  float* out = (float*)d_out;

  const long S  = (long)NB * LQ * BD;   // 4,198,400
  const long S4 = S * 4, S2 = S * 2;
  char* base = (char*)d_ws;
  // layout: X(S4), Xh(S2), B1(S4), Qh(S2), Kh(S2), Vh(S2), Oh(S2), Wt(2MB), orel.
  // aliases (time-shared): Ght = B1..Kh (32MB, pre-layer1 only); satT = Vh (pre-layer1);
  // VhT = B1[0..8.9MB] during self layers (B1 dead until oproj; pads re-zeroed per layer).
  float*    X    = (float*)base;
  ushort_t* Xh   = (ushort_t*)(base + S4);
  float*    B1   = (float*)(base + S4 + S2);
  ushort_t* Qh   = (ushort_t*)(base + 2 * S4 + S2);
  ushort_t* Kh   = (ushort_t*)(base + 2 * S4 + 2 * S2);
  ushort_t* Vh   = (ushort_t*)(base + 2 * S4 + 3 * S2);
  ushort_t* Oh   = (ushort_t*)(base + 2 * S4 + 4 * S2);
  ushort_t* Wt   = (ushort_t*)(base + 2 * S4 + 5 * S2);
  float*    orel = (float*)(base + 2 * S4 + 5 * S2 + 16L * 65536 * 2);
  ushort_t* Ght  = (ushort_t*)B1;
  ushort_t* satT = Vh;
  ushort_t* VhT  = (ushort_t*)B1;

  const long WSZ = (long)BD * BD;
  const long XST = (long)LQ * BD;
  dim3 blk(256);

  k_copy_cast<<<dim3(2048), blk, 0, stream>>>(gv, Xh, S);
  k_wtrans<<<dim3(64, 16), blk, 0, stream>>>(Wq, Wk, Wv, Wo, Wt);

  // ---- layer 0: relay GAT (relay-row reads come straight from gv) ----
  gemm_kv<<<dim3(8, 4, NB), blk, 0, stream>>>(Xh, Wt, 0, Kh, Vh);
  attn_relay<<<dim3(NB, NH), blk, 0, stream>>>(gv, XST, Wq + 0 * WSZ, Kh, Vh, orel);
  rowvec_oproj_ln<<<dim3(NB), blk, 0, stream>>>(orel, Wo + 0 * WSZ, gv, XST,
                                                lg + 0 * BD, lb + 0 * BD, X, XST, Xh, XST);

  // ---- sat mixing: sat = G^T @ sat (pre-transposed MFMA) ----
  k_gtrans<<<dim3(256, NB), blk, 0, stream>>>(graph, Ght);
  k_satT<<<dim3(64, NB), blk, 0, stream>>>(Xh, satT);
  gemm_gtx2<<<dim3(8, 2, NB), blk, 0, stream>>>(Ght, satT, X, Xh);

  // ---- layers 1,2: self GAT (V written transposed by gemm_vT; pads re-zeroed) ----
  for (int l = 1; l <= 2; l++) {
    gemm_qkv<<<dim3(129, 4), blk, 0, stream>>>(Xh, Wt, l, Qh, Kh, NB * LQ);
    gemm_vT<<<dim3(129, 2), blk, 0, stream>>>(Xh, Wt, l, VhT, NB * LQ);
    k_vpad<<<dim3(NB), blk, 0, stream>>>(VhT);
    attn_fa<<<dim3(NB * NH, 9), blk, 0, stream>>>(Qh, Kh, VhT, Oh);
    gemm_oproj<<<dim3(129, 2), blk, 0, stream>>>(Oh, Wt, l, B1, NB * LQ);
    ln_residual<<<dim3(NB * LQ), blk, 0, stream>>>(B1, X, Xh, lg + l * BD, lb + l * BD,
                                                   (l == 2) ? (out + (long)NB * BD) : nullptr);
  }

  // ---- layer 3: final relay GAT -> z (q-projection fused into attn_relay) ----
  gemm_kv<<<dim3(8, 4, NB), blk, 0, stream>>>(Xh, Wt, 3, Kh, Vh);
  attn_relay<<<dim3(NB, NH), blk, 0, stream>>>(X, XST, Wq + 3 * WSZ, Kh, Vh, orel);
  rowvec_oproj_ln<<<dim3(NB), blk, 0, stream>>>(orel, Wo + 3 * WSZ, X, XST,
                                                lg + 3 * BD, lb + 3 * BD, out, BD, nullptr, 0);
}

// Round 17
// 502.249 us; speedup vs baseline: 1.0131x; 1.0131x over previous
//
#include <hip/hip_runtime.h>
#include <hip/hip_bf16.h>
#include <math.h>

#define BD   256    // D
#define NH   8      // heads
#define DH   32     // head dim
#define NB   16     // batch
#define NN   1024   // N
#define LQ   1025   // N+1
#define EPSV 1e-5f
#define KP   1088   // padded key stride for VhT (17*64)

typedef unsigned short ushort_t;
typedef __attribute__((ext_vector_type(8))) short short8;
typedef __attribute__((ext_vector_type(4))) float f32x4;

static __device__ __forceinline__ ushort_t f2b(float x) {
  union { __hip_bfloat16 h; ushort_t u; } cv;
  cv.h = __float2bfloat16(x);
  return cv.u;
}
static __device__ __forceinline__ float b2f(ushort_t u) {
  union { float f; unsigned v; } c; c.v = ((unsigned)u) << 16; return c.f;
}
static __device__ __forceinline__ float fexp2(float x) {
#if defined(__has_builtin)
#if __has_builtin(__builtin_amdgcn_exp2f)
  return __builtin_amdgcn_exp2f(x);
#else
  return exp2f(x);
#endif
#else
  return exp2f(x);
#endif
}
// full-wave (64-lane) butterfly reductions -- no barriers
static __device__ __forceinline__ float wave_sum(float x) {
  #pragma unroll
  for (int off = 1; off < 64; off <<= 1) x += __shfl_xor(x, off);
  return x;
}
static __device__ __forceinline__ float wave_max(float x) {
  #pragma unroll
  for (int off = 1; off < 64; off <<= 1) x = fmaxf(x, __shfl_xor(x, off));
  return x;
}

// ---------------- copy / cast helpers ----------------
// Dataflow: the initial fp32 X copy is only ever READ at relay rows (row % LQ == 0)
// before being overwritten (gemm_gtx2 rewrites all sat rows; all other pre-mixing
// readers consume Xh). Skip the dead 16.7MB of sat-row fp32 writes.
__global__ void k_copy_cast(const float* __restrict__ in, float* __restrict__ X,
                            ushort_t* __restrict__ Xh, long n) {
  long stride = (long)gridDim.x * 256;
  for (long i = (long)blockIdx.x * 256 + threadIdx.x; i < n; i += stride) {
    float v = in[i];
    Xh[i] = f2b(v);
    long row = i >> 8;                 // i / BD
    if (row % LQ == 0) X[i] = v;       // relay rows only
  }
}

// ---------------- weight transpose+cast: Wt[slot][n][k] = bf16(W[k][n]) ----------------
// Q slots (type 0) are pre-scaled by C1 = 1/sqrt(dh) * log2(e) so attention scores
// come out of the MFMA already in exp2 domain.
__global__ __launch_bounds__(256) void k_wtrans(const float* __restrict__ Wq,
                                                const float* __restrict__ Wk,
                                                const float* __restrict__ Wv,
                                                const float* __restrict__ Wo,
                                                ushort_t* __restrict__ Wt) {
  const float C1 = 0.17677669529663687f * 1.4426950408889634f;
  int mat = blockIdx.y;              // 0..15: type*4 + layer
  int type = mat >> 2, layer = mat & 3;
  const float* src = (type == 0) ? Wq : (type == 1) ? Wk : (type == 2) ? Wv : Wo;
  src += (long)layer * BD * BD;
  float scv = (type == 0) ? C1 : 1.f;
  ushort_t* dst = Wt + (long)mat * BD * BD;
  __shared__ float t[32][33];
  int k0 = (blockIdx.x & 7) * 32, n0 = (blockIdx.x >> 3) * 32;
  int tid = threadIdx.x;
  for (int i = tid; i < 1024; i += 256) {
    int kk = i >> 5, nn = i & 31;
    t[kk][nn] = src[(long)(k0 + kk) * BD + n0 + nn];
  }
  __syncthreads();
  for (int i = tid; i < 1024; i += 256) {
    int nn = i >> 5, kk = i & 31;
    dst[(long)(n0 + nn) * BD + k0 + kk] = f2b(t[kk][nn] * scv);
  }
}

// ---------------- G transpose+cast: Ght[b][m][n] = bf16(G[b][n][m]) ----------------
__global__ __launch_bounds__(256) void k_gtrans(const float* __restrict__ G,
                                                ushort_t* __restrict__ Ght) {
  __shared__ ushort_t t[64][65];
  int b = blockIdx.y;
  int m0 = (blockIdx.x & 15) * 64, n0 = (blockIdx.x >> 4) * 64;
  const float* Gb = G + (long)b * NN * NN;
  ushort_t* dst = Ght + (long)b * NN * NN;
  int tid = threadIdx.x;
  #pragma unroll
  for (int rr = 0; rr < 16; rr++) {
    int n = rr * 4 + (tid >> 6);
    int m = tid & 63;
    t[m][n] = f2b(Gb[(long)(n0 + n) * NN + m0 + m]);
  }
  __syncthreads();
  #pragma unroll
  for (int rr = 0; rr < 8; rr++) {
    int m = rr * 8 + (tid >> 5);
    int n2 = (tid & 31) * 2;
    unsigned w = (unsigned)t[m][n2] | ((unsigned)t[m][n2 + 1] << 16);
    *(unsigned*)&dst[(long)(m0 + m) * NN + n0 + n2] = w;
  }
}

// ---------------- sat transpose: satT[b][d][n] = Xh_sat[b][n][d] ----------------
__global__ __launch_bounds__(256) void k_satT(const ushort_t* __restrict__ Xh,
                                              ushort_t* __restrict__ satT) {
  __shared__ ushort_t t[64][65];
  int b = blockIdx.y;
  int n0 = (blockIdx.x & 15) * 64, d0 = (blockIdx.x >> 4) * 64;
  const ushort_t* src = Xh + ((long)b * LQ + 1) * BD;
  ushort_t* dst = satT + (long)b * BD * NN;
  int tid = threadIdx.x;
  #pragma unroll
  for (int rr = 0; rr < 16; rr++) {
    int n = rr * 4 + (tid >> 6);
    int d = tid & 63;
    t[n][d] = src[(long)(n0 + n) * BD + d0 + d];
  }
  __syncthreads();
  #pragma unroll
  for (int rr = 0; rr < 8; rr++) {
    int d = rr * 8 + (tid >> 5);
    int n2 = (tid & 31) * 2;
    unsigned w = (unsigned)t[n2][d] | ((unsigned)t[n2 + 1][d] << 16);
    *(unsigned*)&dst[(long)(d0 + d) * NN + n0 + n2] = w;
  }
}

// ---------------- V transpose: VhT[b][d][key(KP)] = Vh[b*LQ+key][d], zero-padded ----------------
__global__ __launch_bounds__(256) void k_vtrans(const ushort_t* __restrict__ Vh,
                                                ushort_t* __restrict__ VhT) {
  __shared__ ushort_t t[64][65];
  int b = blockIdx.z;
  int n0 = blockIdx.x * 64, d0 = blockIdx.y * 64;
  const ushort_t* src = Vh + (long)b * LQ * BD;
  ushort_t* dst = VhT + (long)b * BD * KP;
  int tid = threadIdx.x;
  #pragma unroll
  for (int rr = 0; rr < 16; rr++) {
    int n = rr * 4 + (tid >> 6);
    int d = tid & 63;
    int key = n0 + n;
    t[n][d] = (key < LQ) ? src[(long)key * BD + d0 + d] : (ushort_t)0;
  }
  __syncthreads();
  #pragma unroll
  for (int rr = 0; rr < 8; rr++) {
    int d = rr * 8 + (tid >> 5);
    int n2 = (tid & 31) * 2;
    unsigned w = (unsigned)t[n2][d] | ((unsigned)t[n2 + 1][d] << 16);
    *(unsigned*)&dst[(long)(d0 + d) * KP + n0 + n2] = w;
  }
}

// ---------------- 128x128 LDS-staged GEMM core (A[M,256] @ W[256(n),256(k)]^T) ----------------
// Async-stage (T14): issue next k-tile global loads to regs, compute current from LDS,
// barrier, ds_write, barrier. 4 waves each own a 64x64 quadrant (4x4 fragments,
// 16 MFMA/k-step). LDS pitch 72 shorts (144B). K=256 in 8 steps of 32.
// NOTE (R11 lesson): do NOT add a residual-read to this epilogue; (R16 lesson): do
// NOT fuse a transposed epilogue either -- both regressed.
static __device__ __forceinline__ void core128(const ushort_t* __restrict__ A,
                                               const ushort_t* __restrict__ W,
                                               ushort_t* As, ushort_t* Bs,
                                               int M, int m0, int n0,
                                               float* __restrict__ Cf,
                                               ushort_t* __restrict__ Ch) {
  int tid = threadIdx.x;
  int wave = tid >> 6, lane = tid & 63;
  int l15 = lane & 15, quad = lane >> 4;
  int wr = wave >> 1, wc = wave & 1;

  int sr = tid >> 2, sc = (tid & 3) * 8;
  int ar0 = m0 + sr;      if (ar0 > M - 1) ar0 = M - 1;
  int ar1 = m0 + sr + 64; if (ar1 > M - 1) ar1 = M - 1;
  const ushort_t* aSrc0 = A + (long)ar0 * 256 + sc;
  const ushort_t* aSrc1 = A + (long)ar1 * 256 + sc;
  const ushort_t* bSrc0 = W + (long)(n0 + sr) * 256 + sc;
  const ushort_t* bSrc1 = bSrc0 + 64 * 256;
  ushort_t* aDst0 = &As[sr * 72 + sc];
  ushort_t* aDst1 = aDst0 + 64 * 72;
  ushort_t* bDst0 = &Bs[sr * 72 + sc];
  ushort_t* bDst1 = bDst0 + 64 * 72;

  {
    uint4 a0 = *(const uint4*)aSrc0;
    uint4 a1 = *(const uint4*)aSrc1;
    uint4 b0 = *(const uint4*)bSrc0;
    uint4 b1 = *(const uint4*)bSrc1;
    *(uint4*)aDst0 = a0; *(uint4*)aDst1 = a1;
    *(uint4*)bDst0 = b0; *(uint4*)bDst1 = b1;
  }
  __syncthreads();

  f32x4 acc[4][4];
  #pragma unroll
  for (int i = 0; i < 4; i++)
    #pragma unroll
    for (int j = 0; j < 4; j++) { acc[i][j][0] = 0.f; acc[i][j][1] = 0.f; acc[i][j][2] = 0.f; acc[i][j][3] = 0.f; }

  for (int ks = 0; ks < 8; ks++) {
    bool more = (ks < 7);
    uint4 na0, na1, nb0, nb1;
    if (more) {
      aSrc0 += 32; aSrc1 += 32; bSrc0 += 32; bSrc1 += 32;
      na0 = *(const uint4*)aSrc0;
      na1 = *(const uint4*)aSrc1;
      nb0 = *(const uint4*)bSrc0;
      nb1 = *(const uint4*)bSrc1;
    }
    short8 af[4], bf[4];
    #pragma unroll
    for (int f = 0; f < 4; f++)
      af[f] = *(const short8*)&As[(wr * 64 + f * 16 + l15) * 72 + quad * 8];
    #pragma unroll
    for (int f = 0; f < 4; f++)
      bf[f] = *(const short8*)&Bs[(wc * 64 + f * 16 + l15) * 72 + quad * 8];
    #pragma unroll
    for (int i = 0; i < 4; i++)
      #pragma unroll
      for (int j = 0; j < 4; j++)
        acc[i][j] = __builtin_amdgcn_mfma_f32_16x16x32_bf16(af[i], bf[j], acc[i][j], 0, 0, 0);
    if (more) {
      __syncthreads();
      *(uint4*)aDst0 = na0;
      *(uint4*)aDst1 = na1;
      *(uint4*)bDst0 = nb0;
      *(uint4*)bDst1 = nb1;
      __syncthreads();
    }
  }

  #pragma unroll
  for (int i = 0; i < 4; i++)
    #pragma unroll
    for (int j = 0; j < 4; j++)
      #pragma unroll
      for (int r = 0; r < 4; r++) {
        int m = m0 + wr * 64 + i * 16 + quad * 4 + r;
        if (m < M) {
          long idx = (long)m * 256 + n0 + wc * 64 + j * 16 + l15;
          if (Cf) Cf[idx] = acc[i][j][r];
          else    Ch[idx] = f2b(acc[i][j][r]);
        }
      }
}

// fused Q/K/V projection: grid (129, 6) ; blockIdx.y = which*2 + n-tile
__global__ __launch_bounds__(256) void gemm_qkv(const ushort_t* __restrict__ Xh,
                                                const ushort_t* __restrict__ Wt, int layer,
                                                ushort_t* __restrict__ Qo,
                                                ushort_t* __restrict__ Ko,
                                                ushort_t* __restrict__ Vo, int M) {
  __shared__ __align__(16) ushort_t As[128 * 72];
  __shared__ __align__(16) ushort_t Bs[128 * 72];
  int which = blockIdx.y >> 1;
  int n0 = (blockIdx.y & 1) * 128;
  const ushort_t* W = Wt + (long)(which * 4 + layer) * 65536;
  ushort_t* C = (which == 0) ? Qo : (which == 1) ? Ko : Vo;
  core128(Xh, W, As, Bs, M, blockIdx.x * 128, n0, nullptr, C);
}

// fused relay K/V projection over sat rows: grid (8, 4, NB); y = which*2 + n-tile
__global__ __launch_bounds__(256) void gemm_kv(const ushort_t* __restrict__ Xh,
                                               const ushort_t* __restrict__ Wt, int layer,
                                               ushort_t* __restrict__ Ko,
                                               ushort_t* __restrict__ Vo) {
  __shared__ __align__(16) ushort_t As[128 * 72];
  __shared__ __align__(16) ushort_t Bs[128 * 72];
  int which = blockIdx.y >> 1;
  int n0 = (blockIdx.y & 1) * 128;
  int b = blockIdx.z;
  const ushort_t* W = Wt + (long)((which + 1) * 4 + layer) * 65536;
  const ushort_t* A = Xh + (long)b * (LQ * BD) + BD;
  ushort_t* C = ((which == 0) ? Ko : Vo) + (long)b * (NN * BD);
  core128(A, W, As, Bs, NN, blockIdx.x * 128, n0, nullptr, C);
}

// o-projection, fp32 out: grid (129, 2)
__global__ __launch_bounds__(256) void gemm_oproj(const ushort_t* __restrict__ Oh,
                                                  const ushort_t* __restrict__ Wt, int layer,
                                                  float* __restrict__ Cf, int M) {
  __shared__ __align__(16) ushort_t As[128 * 72];
  __shared__ __align__(16) ushort_t Bs[128 * 72];
  core128(Oh, Wt + (long)(12 + layer) * 65536, As, Bs, M,
          blockIdx.x * 128, blockIdx.y * 128, Cf, nullptr);
}

// ---------------- graph mixing: X_sat[b,m,d] = sum_n Ght[b,m,n] * satT[b,d,n] ----------------
// LDS-staged tiled GEMM, async-stage (T14). Tile BM=128 x BN=128, 4 waves each 64x64.
// LDS pitch 72 shorts (144B). grid (8, 2, NB) = 256 blocks = 1 block/CU.
__global__ __launch_bounds__(256) void gemm_gtx2(const ushort_t* __restrict__ Ght,
                                                 const ushort_t* __restrict__ satT,
                                                 float* __restrict__ X,
                                                 ushort_t* __restrict__ Xh) {
  __shared__ __align__(16) ushort_t As[128 * 72];
  __shared__ __align__(16) ushort_t Bs[128 * 72];
  int b = blockIdx.z;
  const ushort_t* A  = Ght + (long)b * NN * NN;    // [1024][1024]
  const ushort_t* Bp = satT + (long)b * BD * NN;   // [256][1024]
  int tid = threadIdx.x;
  int wave = tid >> 6, lane = tid & 63;
  int l15 = lane & 15, quad = lane >> 4;
  int wr = wave >> 1, wc = wave & 1;
  int m0 = blockIdx.x * 128, d0 = blockIdx.y * 128;

  int sr = tid >> 2, sc = (tid & 3) * 8;
  const ushort_t* aSrc0 = A  + (long)(m0 + sr) * NN + sc;
  const ushort_t* aSrc1 = aSrc0 + (long)64 * NN;
  const ushort_t* bSrc0 = Bp + (long)(d0 + sr) * NN + sc;
  const ushort_t* bSrc1 = bSrc0 + (long)64 * NN;
  ushort_t* aDst0 = &As[sr * 72 + sc];
  ushort_t* aDst1 = aDst0 + 64 * 72;
  ushort_t* bDst0 = &Bs[sr * 72 + sc];
  ushort_t* bDst1 = bDst0 + 64 * 72;

  {
    uint4 a0 = *(const uint4*)aSrc0;
    uint4 a1 = *(const uint4*)aSrc1;
    uint4 b0 = *(const uint4*)bSrc0;
    uint4 b1 = *(const uint4*)bSrc1;
    *(uint4*)aDst0 = a0; *(uint4*)aDst1 = a1;
    *(uint4*)bDst0 = b0; *(uint4*)bDst1 = b1;
  }
  __syncthreads();

  f32x4 acc[4][4];
  #pragma unroll
  for (int i = 0; i < 4; i++)
    #pragma unroll
    for (int j = 0; j < 4; j++) { acc[i][j][0] = 0.f; acc[i][j][1] = 0.f; acc[i][j][2] = 0.f; acc[i][j][3] = 0.f; }

  for (int ks = 0; ks < 32; ks++) {
    bool more = (ks < 31);
    uint4 na0, na1, nb0, nb1;
    if (more) {
      aSrc0 += 32; aSrc1 += 32; bSrc0 += 32; bSrc1 += 32;
      na0 = *(const uint4*)aSrc0;
      na1 = *(const uint4*)aSrc1;
      nb0 = *(const uint4*)bSrc0;
      nb1 = *(const uint4*)bSrc1;
    }
    short8 af[4], bf[4];
    #pragma unroll
    for (int f = 0; f < 4; f++)
      af[f] = *(const short8*)&As[(wr * 64 + f * 16 + l15) * 72 + quad * 8];
    #pragma unroll
    for (int f = 0; f < 4; f++)
      bf[f] = *(const short8*)&Bs[(wc * 64 + f * 16 + l15) * 72 + quad * 8];
    #pragma unroll
    for (int i = 0; i < 4; i++)
      #pragma unroll
      for (int j = 0; j < 4; j++)
        acc[i][j] = __builtin_amdgcn_mfma_f32_16x16x32_bf16(af[i], bf[j], acc[i][j], 0, 0, 0);
    if (more) {
      __syncthreads();
      *(uint4*)aDst0 = na0;
      *(uint4*)aDst1 = na1;
      *(uint4*)bDst0 = nb0;
      *(uint4*)bDst1 = nb1;
      __syncthreads();
    }
  }

  long xb = ((long)b * LQ + 1) * 256;
  #pragma unroll
  for (int i = 0; i < 4; i++)
    #pragma unroll
    for (int j = 0; j < 4; j++)
      #pragma unroll
      for (int r = 0; r < 4; r++) {
        int m = m0 + wr * 64 + i * 16 + quad * 4 + r;
        int d = d0 + wc * 64 + j * 16 + l15;
        long idx = xb + (long)m * 256 + d;
        X[idx] = acc[i][j][r];
        Xh[idx] = f2b(acc[i][j][r]);
      }
}

// ---------------- attention: single-pass online softmax (deferred rescale) ----------------
// R9-measured version verbatim (67.7 us, 8x-reproduced): single-buffered K/V,
// scalar ls + Lbuf publish + f2b P-packing + balanced pairwise chunk-max tree.
// Rejected variants (ALL measured): MFMA row-sum denominator (R3, 72.5us); inline-asm
// cvt_pk (R6, WRONG on gfx950); max3-style 3-way max nests (R7, 74.9us, serial dep
// chain); K/V double-buffer + packed convert (R10, 70.0us, occupancy 29->24%);
// residual-fused oproj epilogue (R11, +35us); transposed-V gemm epilogue (R16, +6.5us).
// grid (NB*NH, 9); block 256 = 4 waves, 32 q/wave. Q pre-scaled by C1 (in Wt).
// Online max required (layer-1 scores reach +-150 in exp2 domain). Deferred rescale
// (threshold 8 -> p <= 2^8). K/V chunks staged in LDS, reg-staged (T14).
__global__ __launch_bounds__(256) void attn_fa(const ushort_t* __restrict__ Qh,
                                               const ushort_t* __restrict__ Kh,
                                               const ushort_t* __restrict__ VhT,
                                               ushort_t* __restrict__ Oh) {
  __shared__ __align__(16) ushort_t Ps[4][32][72];
  __shared__ __align__(16) ushort_t Kb[64 * 72];   // pitch 72 (144B = 9*16B)
  __shared__ __align__(16) ushort_t Vb[32 * 72];
  __shared__ float Lbuf[4][32];
  int tid = threadIdx.x;
  int wave = tid >> 6, lane = tid & 63;
  int l15 = lane & 15, quad = lane >> 4;
  int b = blockIdx.x >> 3, h = blockIdx.x & 7;
  long hb = ((long)b * LQ) * BD + h * DH;
  long vB = (long)b * BD * KP;
  int hd0 = h * DH;
  int q0 = blockIdx.y * 128 + wave * 32;
  int lq = lane & 48;

  short8 qB[2];
  #pragma unroll
  for (int t = 0; t < 2; t++) {
    int qc = q0 + t * 16 + l15; if (qc > LQ - 1) qc = LQ - 1;
    qB[t] = *(const short8*)&Qh[hb + (long)qc * BD + quad * 8];
  }

  // per-wave staging assignment: 2 segments of 1KB each
  const ushort_t *s0, *s1;
  ushort_t *d0, *d1;
  long stp;
  if (wave < 2) {
    int kt0 = wave * 2, kt1 = kt0 + 1;
    s0 = Kh + hb + (long)(kt0 * 16 + l15) * BD + quad * 8;
    s1 = Kh + hb + (long)(kt1 * 16 + l15) * BD + quad * 8;
    d0 = &Kb[(kt0 * 16 + l15) * 72 + quad * 8];
    d1 = &Kb[(kt1 * 16 + l15) * 72 + quad * 8];
    stp = (long)64 * BD;
  } else {
    int sa = (wave - 2) * 2, sb = sa + 1;   // dt = s>>1, ks = s&1
    s0 = VhT + vB + (long)(hd0 + (sa >> 1) * 16 + l15) * KP + (sa & 1) * 32 + quad * 8;
    s1 = VhT + vB + (long)(hd0 + (sb >> 1) * 16 + l15) * KP + (sb & 1) * 32 + quad * 8;
    d0 = &Vb[((sa >> 1) * 16 + l15) * 72 + (sa & 1) * 32 + quad * 8];
    d1 = &Vb[((sb >> 1) * 16 + l15) * 72 + (sb & 1) * 32 + quad * 8];
    stp = 64;
  }
  {
    uint4 r0 = *(const uint4*)s0;
    uint4 r1 = *(const uint4*)s1;
    *(uint4*)d0 = r0;
    *(uint4*)d1 = r1;
  }
  __syncthreads();

  f32x4 o[2][2];
  #pragma unroll
  for (int t = 0; t < 2; t++)
    #pragma unroll
    for (int dt = 0; dt < 2; dt++) { o[t][dt][0] = 0.f; o[t][dt][1] = 0.f; o[t][dt][2] = 0.f; o[t][dt][3] = 0.f; }
  float m[2] = {-1e30f, -1e30f};
  float ls[2] = {0.f, 0.f};
  f32x4 zf; zf[0] = 0.f; zf[1] = 0.f; zf[2] = 0.f; zf[3] = 0.f;

  for (int c = 0; c < 17; c++) {
    bool more = (c < 16);
    uint4 n0, n1;
    if (more) {
      if (c == 15 && wave < 2) {
        // chunk 16 K rows (1024..1087) all clamp to row 1024; masked in compute
        const ushort_t* cl = Kh + hb + (long)(LQ - 1) * BD + quad * 8;
        n0 = *(const uint4*)cl;
        n1 = n0;
      } else {
        s0 += stp; s1 += stp;
        n0 = *(const uint4*)s0;
        n1 = *(const uint4*)s1;
      }
    }
    short8 ka[4];
    #pragma unroll
    for (int kt = 0; kt < 4; kt++)
      ka[kt] = *(const short8*)&Kb[(kt * 16 + l15) * 72 + quad * 8];

    bool tail = (c == 16);
    #pragma unroll
    for (int t = 0; t < 2; t++) {
      f32x4 s[4];
      #pragma unroll
      for (int kt = 0; kt < 4; kt++)
        s[kt] = __builtin_amdgcn_mfma_f32_16x16x32_bf16(ka[kt], qB[t], zf, 0, 0, 0);
      if (tail) {
        // only key 1024 (kt=0, quad=0, r=0) is valid; mask the rest
        #pragma unroll
        for (int kt = 0; kt < 4; kt++)
          #pragma unroll
          for (int r = 0; r < 4; r++)
            if (kt + r) s[kt][r] = -1e30f;
        if (quad) s[0][0] = -1e30f;
      }
      // chunk row-max (balanced pairwise tree -- max ILP; scores already in exp2 domain)
      float cm = fmaxf(fmaxf(s[0][0], s[0][1]), fmaxf(s[0][2], s[0][3]));
      cm = fmaxf(cm, fmaxf(fmaxf(s[1][0], s[1][1]), fmaxf(s[1][2], s[1][3])));
      cm = fmaxf(cm, fmaxf(fmaxf(s[2][0], s[2][1]), fmaxf(s[2][2], s[2][3])));
      cm = fmaxf(cm, fmaxf(fmaxf(s[3][0], s[3][1]), fmaxf(s[3][2], s[3][3])));
      cm = fmaxf(cm, __shfl_xor(cm, 16));
      cm = fmaxf(cm, __shfl_xor(cm, 32));
      if (__any(cm > m[t] + 8.f)) {
        float mn = fmaxf(m[t], cm);
        float f = fexp2(m[t] - mn);
        ls[t] *= f;
        m[t] = mn;
        #pragma unroll
        for (int r = 0; r < 4; r++) {
          // o-row q = quad*4+r lives at lane l15 = quad*4+r (same quad group)
          float fr = __shfl(f, lq | (quad * 4 + r));
          o[t][0][r] *= fr;
          o[t][1][r] *= fr;
        }
      }
      float mt = m[t];
      #pragma unroll
      for (int kt = 0; kt < 4; kt++) {
        float p0 = fexp2(s[kt][0] - mt);
        float p1 = fexp2(s[kt][1] - mt);
        float p2 = fexp2(s[kt][2] - mt);
        float p3 = fexp2(s[kt][3] - mt);
        ls[t] += (p0 + p1) + (p2 + p3);
        unsigned lo = (unsigned)f2b(p0) | ((unsigned)f2b(p1) << 16);
        unsigned hi = (unsigned)f2b(p2) | ((unsigned)f2b(p3) << 16);
        uint2 w; w.x = lo; w.y = hi;
        *(uint2*)&Ps[wave][t * 16 + l15][kt * 16 + quad * 4] = w;
      }
    }
    // PV: o[q][d] += P[q][keys] * V[keys][d]  (Ps wave-private)
    short8 vb[2][2];
    #pragma unroll
    for (int dt = 0; dt < 2; dt++)
      #pragma unroll
      for (int ks = 0; ks < 2; ks++)
        vb[ks][dt] = *(const short8*)&Vb[(dt * 16 + l15) * 72 + ks * 32 + quad * 8];
    #pragma unroll
    for (int ks = 0; ks < 2; ks++) {
      short8 pa0 = *(const short8*)&Ps[wave][l15][ks * 32 + quad * 8];
      short8 pa1 = *(const short8*)&Ps[wave][16 + l15][ks * 32 + quad * 8];
      #pragma unroll
      for (int dt = 0; dt < 2; dt++) {
        o[0][dt] = __builtin_amdgcn_mfma_f32_16x16x32_bf16(pa0, vb[ks][dt], o[0][dt], 0, 0, 0);
        o[1][dt] = __builtin_amdgcn_mfma_f32_16x16x32_bf16(pa1, vb[ks][dt], o[1][dt], 0, 0, 0);
      }
    }
    if (more) {
      __syncthreads();           // everyone done reading Kb/Vb
      *(uint4*)d0 = n0;          // waits vmcnt via reg dependency
      *(uint4*)d1 = n1;
      __syncthreads();           // chunk c+1 staged
    }
  }
  // denominator: reduce quad-copies, publish via LDS with a full barrier
  #pragma unroll
  for (int t = 0; t < 2; t++) {
    ls[t] += __shfl_xor(ls[t], 16);
    ls[t] += __shfl_xor(ls[t], 32);
  }
  if (quad == 0) {
    Lbuf[wave][l15] = ls[0];
    Lbuf[wave][16 + l15] = ls[1];
  }
  __syncthreads();
  #pragma unroll
  for (int mt = 0; mt < 2; mt++) {
    f32x4 lv = *(const f32x4*)&Lbuf[wave][mt * 16 + quad * 4];
    #pragma unroll
    for (int r = 0; r < 4; r++) {
      int row = q0 + mt * 16 + quad * 4 + r;
      if (row < LQ) {
        float den = lv[r];
        float inv = (den > 0.f) ? 1.f / den : 0.f;
        #pragma unroll
        for (int dt = 0; dt < 2; dt++)
          Oh[hb + (long)row * BD + dt * 16 + l15] = f2b(o[mt][dt][r] * inv);
      }
    }
  }
}

// ---------------- relay attention: Lq=1, Lk=1024, bf16 K/V ----------------
// Barrier-light (R13) + fused q-projection (R15): each (b,h) block computes its
// own 32-wide q slice directly. X may be gv (layer 0) -- same row stride.
__global__ __launch_bounds__(256) void attn_relay(const float* __restrict__ X, long xstride,
                                                  const float* __restrict__ Wq,
                                                  const ushort_t* __restrict__ K,
                                                  const ushort_t* __restrict__ V,
                                                  float* __restrict__ o) {
  int b = blockIdx.x, h = blockIdx.y;
  int tid = threadIdx.x;
  int wave = tid >> 6, lane = tid & 63;
  const float scale = 0.17677669529663687f;
  __shared__ float s[NN];
  __shared__ float xs[BD];
  __shared__ float qs[DH];
  __shared__ float pmax[4], psum[4];
  __shared__ float part[8][33];
  // --- fused q projection: qs[d] = X[b] . Wq[:, h*DH + d] ---
  xs[tid] = X[(long)b * xstride + tid];
  __syncthreads();
  {
    int d = tid & 31, slice = tid >> 5;
    const float* wq = Wq + h * DH + d;
    float partial = 0.f;
    #pragma unroll
    for (int kk = 0; kk < 32; kk++) {
      int k = slice * 32 + kk;
      partial += xs[k] * wq[(long)k * BD];
    }
    part[slice][d] = partial;
  }
  __syncthreads();
  if (tid < DH) {
    float ss = 0.f;
    #pragma unroll
    for (int t = 0; t < 8; t++) ss += part[t][tid];
    qs[tid] = ss;
  }
  __syncthreads();
  // --- scores ---
  long base = ((long)b * NN) * BD + h * DH;
  float lm = -1e30f;
  for (int k = tid; k < NN; k += 256) {
    float dot = 0.f;
    const ushort_t* kr = &K[base + (long)k * BD];
    #pragma unroll
    for (int d2 = 0; d2 < 16; d2++) {
      unsigned w = *(const unsigned*)&kr[d2 * 2];
      dot += qs[d2 * 2] * b2f((ushort_t)(w & 0xffff)) + qs[d2 * 2 + 1] * b2f((ushort_t)(w >> 16));
    }
    float sv = dot * scale;
    s[k] = sv;
    lm = fmaxf(lm, sv);
  }
  lm = wave_max(lm);
  if (lane == 0) pmax[wave] = lm;
  __syncthreads();          // s[] visible + pmax visible
  float mx = fmaxf(fmaxf(pmax[0], pmax[1]), fmaxf(pmax[2], pmax[3]));
  float sm = 0.f;
  for (int k = tid; k < NN; k += 256) {
    float p = __expf(s[k] - mx);
    s[k] = p;
    sm += p;
  }
  sm = wave_sum(sm);
  if (lane == 0) psum[wave] = sm;
  __syncthreads();          // exp'd s[] visible + psum visible
  float inv = 1.f / (((psum[0] + psum[1]) + (psum[2] + psum[3])));
  int d = tid & 31, slice = tid >> 5;
  float acc = 0.f;
  for (int k = slice; k < NN; k += 8) acc += s[k] * b2f(V[base + (long)k * BD + d]);
  part[slice][d] = acc;
  __syncthreads();
  if (tid < DH) {
    float ss = 0.f;
    #pragma unroll
    for (int t = 0; t < 8; t++) ss += part[t][tid];
    o[(long)b * BD + h * DH + tid] = ss * inv;
  }
}

// ---------------- relay row ops (fp32 weights; tiny) ----------------
__global__ __launch_bounds__(256) void rowvec_oproj_ln(const float* __restrict__ o,
                                                       const float* __restrict__ Wo,
                                                       const float* __restrict__ Xres, long xstride,
                                                       const float* __restrict__ g,
                                                       const float* __restrict__ beta,
                                                       float* __restrict__ dst, long dstride,
                                                       ushort_t* __restrict__ dsth, long dhstride) {
  int b = blockIdx.x, tid = threadIdx.x;
  int wave = tid >> 6, lane = tid & 63;
  __shared__ float xs[BD];
  __shared__ float ps[4], pq[4];
  xs[tid] = o[(long)b * BD + tid];
  __syncthreads();
  float acc = 0.f;
  for (int k = 0; k < BD; k++) acc += xs[k] * Wo[(long)k * BD + tid];
  float v = acc + Xres[(long)b * xstride + tid];
  float sum = wave_sum(v);
  float sq  = wave_sum(v * v);
  if (lane == 0) { ps[wave] = sum; pq[wave] = sq; }
  __syncthreads();
  float ts = (ps[0] + ps[1]) + (ps[2] + ps[3]);
  float tq = (pq[0] + pq[1]) + (pq[2] + pq[3]);
  float mu = ts * (1.f / BD);
  float var = tq * (1.f / BD) - mu * mu;
  float y = (v - mu) * rsqrtf(var + EPSV) * g[tid] + beta[tid];
  dst[(long)b * dstride + tid] = y;
  if (dsth) dsth[(long)b * dhstride + tid] = f2b(y);
}

// ln_residual with optional fused sat-output store (replaces k_sat_out at layer 2):
// sat_out[b][r-1][:] = y for sat rows r>=1. Wave-shfl reduction: 1 barrier (was 9).
// When sat_out is set (layer 2), X sat-row writes are DEAD (only relay rows of X
// are read after layer 2; sat output flows through sat_out) -- skip them.
__global__ __launch_bounds__(256) void ln_residual(const float* __restrict__ OP,
                                                   float* __restrict__ X,
                                                   ushort_t* __restrict__ Xh,
                                                   const float* __restrict__ g,
                                                   const float* __restrict__ beta,
                                                   float* __restrict__ sat_out) {
  long r = blockIdx.x;
  int tid = threadIdx.x;
  int wave = tid >> 6, lane = tid & 63;
  __shared__ float ps[4], pq[4];
  float v = OP[r * BD + tid] + X[r * BD + tid];
  float sum = wave_sum(v);
  float sq  = wave_sum(v * v);
  if (lane == 0) { ps[wave] = sum; pq[wave] = sq; }
  __syncthreads();
  float ts = (ps[0] + ps[1]) + (ps[2] + ps[3]);
  float tq = (pq[0] + pq[1]) + (pq[2] + pq[3]);
  float mu = ts * (1.f / BD);
  float var = tq * (1.f / BD) - mu * mu;
  float y = (v - mu) * rsqrtf(var + EPSV) * g[tid] + beta[tid];
  Xh[r * BD + tid] = f2b(y);
  if (sat_out) {
    long b = r / LQ;
    long rr = r - b * LQ;
    if (rr > 0)
      sat_out[(b * (long)NN + (rr - 1)) * BD + tid] = y;
    else
      X[r * BD + tid] = y;       // relay row still needed by layer 3
  } else {
    X[r * BD + tid] = y;
  }
}

// ---------------- launch ----------------
extern "C" void kernel_launch(void* const* d_in, const int* in_sizes, int n_in,
                              void* d_out, int out_size, void* d_ws, size_t ws_size,
                              hipStream_t stream) {
  const float* gv    = (const float*)d_in[0];
  const float* graph = (const float*)d_in[1];
  const float* Wq    = (const float*)d_in[2];
  const float* Wk    = (const float*)d_in[3];
  const float* Wv    = (const float*)d_in[4];
  const float* Wo    = (const float*)d_in[5];
  const float* lg    = (const float*)d_in[6];
  const float* lb    = (const float*)d_in[7];
  float* out = (float*)d_out;

  const long S  = (long)NB * LQ * BD;   // 4,198,400
  const long S4 = S * 4, S2 = S * 2;
  char* base = (char*)d_ws;
  // layout: X(S4), Xh(S2), B1(S4), Qh(S2), Kh(S2), Vh(S2), Oh(S2), Wt(2MB), orel.
  // aliases (time-shared): Ght = B1..Kh (32MB, pre-layer1 only); satT = Vh (pre-layer1);
  // VhT = B1[0..8.9MB] during self layers (B1 dead until oproj).
  float*    X    = (float*)base;
  ushort_t* Xh   = (ushort_t*)(base + S4);
  float*    B1   = (float*)(base + S4 + S2);
  ushort_t* Qh   = (ushort_t*)(base + 2 * S4 + S2);
  ushort_t* Kh   = (ushort_t*)(base + 2 * S4 + 2 * S2);
  ushort_t* Vh   = (ushort_t*)(base + 2 * S4 + 3 * S2);
  ushort_t* Oh   = (ushort_t*)(base + 2 * S4 + 4 * S2);
  ushort_t* Wt   = (ushort_t*)(base + 2 * S4 + 5 * S2);
  float*    orel = (float*)(base + 2 * S4 + 5 * S2 + 16L * 65536 * 2);
  ushort_t* Ght  = (ushort_t*)B1;
  ushort_t* satT = Vh;
  ushort_t* VhT  = (ushort_t*)B1;

  const long WSZ = (long)BD * BD;
  const long XST = (long)LQ * BD;
  dim3 blk(256);

  k_copy_cast<<<dim3(2048), blk, 0, stream>>>(gv, X, Xh, S);
  k_wtrans<<<dim3(64, 16), blk, 0, stream>>>(Wq, Wk, Wv, Wo, Wt);

  // ---- layer 0: relay GAT (q-projection fused into attn_relay) ----
  gemm_kv<<<dim3(8, 4, NB), blk, 0, stream>>>(Xh, Wt, 0, Kh, Vh);
  attn_relay<<<dim3(NB, NH), blk, 0, stream>>>(X, XST, Wq + 0 * WSZ, Kh, Vh, orel);
  rowvec_oproj_ln<<<dim3(NB), blk, 0, stream>>>(orel, Wo + 0 * WSZ, X, XST,
                                                lg + 0 * BD, lb + 0 * BD, X, XST, Xh, XST);

  // ---- sat mixing: sat = G^T @ sat (pre-transposed MFMA) ----
  k_gtrans<<<dim3(256, NB), blk, 0, stream>>>(graph, Ght);
  k_satT<<<dim3(64, NB), blk, 0, stream>>>(Xh, satT);
  gemm_gtx2<<<dim3(8, 2, NB), blk, 0, stream>>>(Ght, satT, X, Xh);

  // ---- layers 1,2: self GAT (layer 2's ln_residual also emits sat_u) ----
  for (int l = 1; l <= 2; l++) {
    gemm_qkv<<<dim3(129, 6), blk, 0, stream>>>(Xh, Wt, l, Qh, Kh, Vh, NB * LQ);
    k_vtrans<<<dim3(17, 4, NB), blk, 0, stream>>>(Vh, VhT);
    attn_fa<<<dim3(NB * NH, 9), blk, 0, stream>>>(Qh, Kh, VhT, Oh);
    gemm_oproj<<<dim3(129, 2), blk, 0, stream>>>(Oh, Wt, l, B1, NB * LQ);
    ln_residual<<<dim3(NB * LQ), blk, 0, stream>>>(B1, X, Xh, lg + l * BD, lb + l * BD,
                                                   (l == 2) ? (out + (long)NB * BD) : nullptr);
  }

  // ---- layer 3: final relay GAT -> z (q-projection fused into attn_relay) ----
  gemm_kv<<<dim3(8, 4, NB), blk, 0, stream>>>(Xh, Wt, 3, Kh, Vh);
  attn_relay<<<dim3(NB, NH), blk, 0, stream>>>(X, XST, Wq + 3 * WSZ, Kh, Vh, orel);
  rowvec_oproj_ln<<<dim3(NB), blk, 0, stream>>>(orel, Wo + 3 * WSZ, X, XST,
                                                lg + 3 * BD, lb + 3 * BD, out, BD, nullptr, 0);
}

// Round 18
// 500.280 us; speedup vs baseline: 1.0171x; 1.0039x over previous
//
#include <hip/hip_runtime.h>
#include <hip/hip_bf16.h>
#include <math.h>

#define BD   256    // D
#define NH   8      // heads
#define DH   32     // head dim
#define NB   16     // batch
#define NN   1024   // N
#define LQ   1025   // N+1
#define EPSV 1e-5f
#define KP   1088   // padded key stride for VhT (17*64)

typedef unsigned short ushort_t;
typedef __attribute__((ext_vector_type(8))) short short8;
typedef __attribute__((ext_vector_type(4))) float f32x4;

static __device__ __forceinline__ ushort_t f2b(float x) {
  union { __hip_bfloat16 h; ushort_t u; } cv;
  cv.h = __float2bfloat16(x);
  return cv.u;
}
static __device__ __forceinline__ float b2f(ushort_t u) {
  union { float f; unsigned v; } c; c.v = ((unsigned)u) << 16; return c.f;
}
static __device__ __forceinline__ float fexp2(float x) {
#if defined(__has_builtin)
#if __has_builtin(__builtin_amdgcn_exp2f)
  return __builtin_amdgcn_exp2f(x);
#else
  return exp2f(x);
#endif
#else
  return exp2f(x);
#endif
}
// full-wave (64-lane) butterfly reductions -- no barriers
static __device__ __forceinline__ float wave_sum(float x) {
  #pragma unroll
  for (int off = 1; off < 64; off <<= 1) x += __shfl_xor(x, off);
  return x;
}
static __device__ __forceinline__ float wave_max(float x) {
  #pragma unroll
  for (int off = 1; off < 64; off <<= 1) x = fmaxf(x, __shfl_xor(x, off));
  return x;
}
// 8-element bf16 dot against fp32 q-slice (pairs in original accumulation order)
static __device__ __forceinline__ float dot8(uint4 w, const float* q) {
  float r = q[0] * b2f((ushort_t)(w.x & 0xffff)) + q[1] * b2f((ushort_t)(w.x >> 16));
  r += q[2] * b2f((ushort_t)(w.y & 0xffff)) + q[3] * b2f((ushort_t)(w.y >> 16));
  r += q[4] * b2f((ushort_t)(w.z & 0xffff)) + q[5] * b2f((ushort_t)(w.z >> 16));
  r += q[6] * b2f((ushort_t)(w.w & 0xffff)) + q[7] * b2f((ushort_t)(w.w >> 16));
  return r;
}

// ---------------- copy / cast helpers ----------------
// Dataflow: the initial fp32 X copy is only ever READ at relay rows (row % LQ == 0)
// before being overwritten (gemm_gtx2 rewrites all sat rows; all other pre-mixing
// readers consume Xh). Skip the dead 16.7MB of sat-row fp32 writes.
__global__ void k_copy_cast(const float* __restrict__ in, float* __restrict__ X,
                            ushort_t* __restrict__ Xh, long n) {
  long stride = (long)gridDim.x * 256;
  for (long i = (long)blockIdx.x * 256 + threadIdx.x; i < n; i += stride) {
    float v = in[i];
    Xh[i] = f2b(v);
    long row = i >> 8;                 // i / BD
    if (row % LQ == 0) X[i] = v;       // relay rows only
  }
}

// ---------------- weight transpose+cast: Wt[slot][n][k] = bf16(W[k][n]) ----------------
// Q slots (type 0) are pre-scaled by C1 = 1/sqrt(dh) * log2(e) so attention scores
// come out of the MFMA already in exp2 domain.
__global__ __launch_bounds__(256) void k_wtrans(const float* __restrict__ Wq,
                                                const float* __restrict__ Wk,
                                                const float* __restrict__ Wv,
                                                const float* __restrict__ Wo,
                                                ushort_t* __restrict__ Wt) {
  const float C1 = 0.17677669529663687f * 1.4426950408889634f;
  int mat = blockIdx.y;              // 0..15: type*4 + layer
  int type = mat >> 2, layer = mat & 3;
  const float* src = (type == 0) ? Wq : (type == 1) ? Wk : (type == 2) ? Wv : Wo;
  src += (long)layer * BD * BD;
  float scv = (type == 0) ? C1 : 1.f;
  ushort_t* dst = Wt + (long)mat * BD * BD;
  __shared__ float t[32][33];
  int k0 = (blockIdx.x & 7) * 32, n0 = (blockIdx.x >> 3) * 32;
  int tid = threadIdx.x;
  for (int i = tid; i < 1024; i += 256) {
    int kk = i >> 5, nn = i & 31;
    t[kk][nn] = src[(long)(k0 + kk) * BD + n0 + nn];
  }
  __syncthreads();
  for (int i = tid; i < 1024; i += 256) {
    int nn = i >> 5, kk = i & 31;
    dst[(long)(n0 + nn) * BD + k0 + kk] = f2b(t[kk][nn] * scv);
  }
}

// ---------------- G transpose+cast: Ght[b][m][n] = bf16(G[b][n][m]) ----------------
__global__ __launch_bounds__(256) void k_gtrans(const float* __restrict__ G,
                                                ushort_t* __restrict__ Ght) {
  __shared__ ushort_t t[64][65];
  int b = blockIdx.y;
  int m0 = (blockIdx.x & 15) * 64, n0 = (blockIdx.x >> 4) * 64;
  const float* Gb = G + (long)b * NN * NN;
  ushort_t* dst = Ght + (long)b * NN * NN;
  int tid = threadIdx.x;
  #pragma unroll
  for (int rr = 0; rr < 16; rr++) {
    int n = rr * 4 + (tid >> 6);
    int m = tid & 63;
    t[m][n] = f2b(Gb[(long)(n0 + n) * NN + m0 + m]);
  }
  __syncthreads();
  #pragma unroll
  for (int rr = 0; rr < 8; rr++) {
    int m = rr * 8 + (tid >> 5);
    int n2 = (tid & 31) * 2;
    unsigned w = (unsigned)t[m][n2] | ((unsigned)t[m][n2 + 1] << 16);
    *(unsigned*)&dst[(long)(m0 + m) * NN + n0 + n2] = w;
  }
}

// ---------------- sat transpose: satT[b][d][n] = Xh_sat[b][n][d] ----------------
__global__ __launch_bounds__(256) void k_satT(const ushort_t* __restrict__ Xh,
                                              ushort_t* __restrict__ satT) {
  __shared__ ushort_t t[64][65];
  int b = blockIdx.y;
  int n0 = (blockIdx.x & 15) * 64, d0 = (blockIdx.x >> 4) * 64;
  const ushort_t* src = Xh + ((long)b * LQ + 1) * BD;
  ushort_t* dst = satT + (long)b * BD * NN;
  int tid = threadIdx.x;
  #pragma unroll
  for (int rr = 0; rr < 16; rr++) {
    int n = rr * 4 + (tid >> 6);
    int d = tid & 63;
    t[n][d] = src[(long)(n0 + n) * BD + d0 + d];
  }
  __syncthreads();
  #pragma unroll
  for (int rr = 0; rr < 8; rr++) {
    int d = rr * 8 + (tid >> 5);
    int n2 = (tid & 31) * 2;
    unsigned w = (unsigned)t[n2][d] | ((unsigned)t[n2 + 1][d] << 16);
    *(unsigned*)&dst[(long)(d0 + d) * NN + n0 + n2] = w;
  }
}

// ---------------- V transpose: VhT[b][d][key(KP)] = Vh[b*LQ+key][d], zero-padded ----------------
__global__ __launch_bounds__(256) void k_vtrans(const ushort_t* __restrict__ Vh,
                                                ushort_t* __restrict__ VhT) {
  __shared__ ushort_t t[64][65];
  int b = blockIdx.z;
  int n0 = blockIdx.x * 64, d0 = blockIdx.y * 64;
  const ushort_t* src = Vh + (long)b * LQ * BD;
  ushort_t* dst = VhT + (long)b * BD * KP;
  int tid = threadIdx.x;
  #pragma unroll
  for (int rr = 0; rr < 16; rr++) {
    int n = rr * 4 + (tid >> 6);
    int d = tid & 63;
    int key = n0 + n;
    t[n][d] = (key < LQ) ? src[(long)key * BD + d0 + d] : (ushort_t)0;
  }
  __syncthreads();
  #pragma unroll
  for (int rr = 0; rr < 8; rr++) {
    int d = rr * 8 + (tid >> 5);
    int n2 = (tid & 31) * 2;
    unsigned w = (unsigned)t[n2][d] | ((unsigned)t[n2 + 1][d] << 16);
    *(unsigned*)&dst[(long)(d0 + d) * KP + n0 + n2] = w;
  }
}

// ---------------- 128x128 LDS-staged GEMM core (A[M,256] @ W[256(n),256(k)]^T) ----------------
// Async-stage (T14): issue next k-tile global loads to regs, compute current from LDS,
// barrier, ds_write, barrier. 4 waves each own a 64x64 quadrant (4x4 fragments,
// 16 MFMA/k-step). LDS pitch 72 shorts (144B). K=256 in 8 steps of 32.
// NOTE (R11 lesson): do NOT add a residual-read to this epilogue; (R16 lesson): do
// NOT fuse a transposed epilogue either -- both regressed.
static __device__ __forceinline__ void core128(const ushort_t* __restrict__ A,
                                               const ushort_t* __restrict__ W,
                                               ushort_t* As, ushort_t* Bs,
                                               int M, int m0, int n0,
                                               float* __restrict__ Cf,
                                               ushort_t* __restrict__ Ch) {
  int tid = threadIdx.x;
  int wave = tid >> 6, lane = tid & 63;
  int l15 = lane & 15, quad = lane >> 4;
  int wr = wave >> 1, wc = wave & 1;

  int sr = tid >> 2, sc = (tid & 3) * 8;
  int ar0 = m0 + sr;      if (ar0 > M - 1) ar0 = M - 1;
  int ar1 = m0 + sr + 64; if (ar1 > M - 1) ar1 = M - 1;
  const ushort_t* aSrc0 = A + (long)ar0 * 256 + sc;
  const ushort_t* aSrc1 = A + (long)ar1 * 256 + sc;
  const ushort_t* bSrc0 = W + (long)(n0 + sr) * 256 + sc;
  const ushort_t* bSrc1 = bSrc0 + 64 * 256;
  ushort_t* aDst0 = &As[sr * 72 + sc];
  ushort_t* aDst1 = aDst0 + 64 * 72;
  ushort_t* bDst0 = &Bs[sr * 72 + sc];
  ushort_t* bDst1 = bDst0 + 64 * 72;

  {
    uint4 a0 = *(const uint4*)aSrc0;
    uint4 a1 = *(const uint4*)aSrc1;
    uint4 b0 = *(const uint4*)bSrc0;
    uint4 b1 = *(const uint4*)bSrc1;
    *(uint4*)aDst0 = a0; *(uint4*)aDst1 = a1;
    *(uint4*)bDst0 = b0; *(uint4*)bDst1 = b1;
  }
  __syncthreads();

  f32x4 acc[4][4];
  #pragma unroll
  for (int i = 0; i < 4; i++)
    #pragma unroll
    for (int j = 0; j < 4; j++) { acc[i][j][0] = 0.f; acc[i][j][1] = 0.f; acc[i][j][2] = 0.f; acc[i][j][3] = 0.f; }

  for (int ks = 0; ks < 8; ks++) {
    bool more = (ks < 7);
    uint4 na0, na1, nb0, nb1;
    if (more) {
      aSrc0 += 32; aSrc1 += 32; bSrc0 += 32; bSrc1 += 32;
      na0 = *(const uint4*)aSrc0;
      na1 = *(const uint4*)aSrc1;
      nb0 = *(const uint4*)bSrc0;
      nb1 = *(const uint4*)bSrc1;
    }
    short8 af[4], bf[4];
    #pragma unroll
    for (int f = 0; f < 4; f++)
      af[f] = *(const short8*)&As[(wr * 64 + f * 16 + l15) * 72 + quad * 8];
    #pragma unroll
    for (int f = 0; f < 4; f++)
      bf[f] = *(const short8*)&Bs[(wc * 64 + f * 16 + l15) * 72 + quad * 8];
    #pragma unroll
    for (int i = 0; i < 4; i++)
      #pragma unroll
      for (int j = 0; j < 4; j++)
        acc[i][j] = __builtin_amdgcn_mfma_f32_16x16x32_bf16(af[i], bf[j], acc[i][j], 0, 0, 0);
    if (more) {
      __syncthreads();
      *(uint4*)aDst0 = na0;
      *(uint4*)aDst1 = na1;
      *(uint4*)bDst0 = nb0;
      *(uint4*)bDst1 = nb1;
      __syncthreads();
    }
  }

  #pragma unroll
  for (int i = 0; i < 4; i++)
    #pragma unroll
    for (int j = 0; j < 4; j++)
      #pragma unroll
      for (int r = 0; r < 4; r++) {
        int m = m0 + wr * 64 + i * 16 + quad * 4 + r;
        if (m < M) {
          long idx = (long)m * 256 + n0 + wc * 64 + j * 16 + l15;
          if (Cf) Cf[idx] = acc[i][j][r];
          else    Ch[idx] = f2b(acc[i][j][r]);
        }
      }
}

// fused Q/K/V projection: grid (129, 6) ; blockIdx.y = which*2 + n-tile
__global__ __launch_bounds__(256) void gemm_qkv(const ushort_t* __restrict__ Xh,
                                                const ushort_t* __restrict__ Wt, int layer,
                                                ushort_t* __restrict__ Qo,
                                                ushort_t* __restrict__ Ko,
                                                ushort_t* __restrict__ Vo, int M) {
  __shared__ __align__(16) ushort_t As[128 * 72];
  __shared__ __align__(16) ushort_t Bs[128 * 72];
  int which = blockIdx.y >> 1;
  int n0 = (blockIdx.y & 1) * 128;
  const ushort_t* W = Wt + (long)(which * 4 + layer) * 65536;
  ushort_t* C = (which == 0) ? Qo : (which == 1) ? Ko : Vo;
  core128(Xh, W, As, Bs, M, blockIdx.x * 128, n0, nullptr, C);
}

// fused relay K/V projection over sat rows: grid (8, 4, NB); y = which*2 + n-tile
__global__ __launch_bounds__(256) void gemm_kv(const ushort_t* __restrict__ Xh,
                                               const ushort_t* __restrict__ Wt, int layer,
                                               ushort_t* __restrict__ Ko,
                                               ushort_t* __restrict__ Vo) {
  __shared__ __align__(16) ushort_t As[128 * 72];
  __shared__ __align__(16) ushort_t Bs[128 * 72];
  int which = blockIdx.y >> 1;
  int n0 = (blockIdx.y & 1) * 128;
  int b = blockIdx.z;
  const ushort_t* W = Wt + (long)((which + 1) * 4 + layer) * 65536;
  const ushort_t* A = Xh + (long)b * (LQ * BD) + BD;
  ushort_t* C = ((which == 0) ? Ko : Vo) + (long)b * (NN * BD);
  core128(A, W, As, Bs, NN, blockIdx.x * 128, n0, nullptr, C);
}

// o-projection, fp32 out: grid (129, 2)
__global__ __launch_bounds__(256) void gemm_oproj(const ushort_t* __restrict__ Oh,
                                                  const ushort_t* __restrict__ Wt, int layer,
                                                  float* __restrict__ Cf, int M) {
  __shared__ __align__(16) ushort_t As[128 * 72];
  __shared__ __align__(16) ushort_t Bs[128 * 72];
  core128(Oh, Wt + (long)(12 + layer) * 65536, As, Bs, M,
          blockIdx.x * 128, blockIdx.y * 128, Cf, nullptr);
}

// ---------------- graph mixing: X_sat[b,m,d] = sum_n Ght[b,m,n] * satT[b,d,n] ----------------
// LDS-staged tiled GEMM, async-stage (T14). Tile BM=128 x BN=128, 4 waves each 64x64.
// LDS pitch 72 shorts (144B). grid (8, 2, NB) = 256 blocks = 1 block/CU.
__global__ __launch_bounds__(256) void gemm_gtx2(const ushort_t* __restrict__ Ght,
                                                 const ushort_t* __restrict__ satT,
                                                 float* __restrict__ X,
                                                 ushort_t* __restrict__ Xh) {
  __shared__ __align__(16) ushort_t As[128 * 72];
  __shared__ __align__(16) ushort_t Bs[128 * 72];
  int b = blockIdx.z;
  const ushort_t* A  = Ght + (long)b * NN * NN;    // [1024][1024]
  const ushort_t* Bp = satT + (long)b * BD * NN;   // [256][1024]
  int tid = threadIdx.x;
  int wave = tid >> 6, lane = tid & 63;
  int l15 = lane & 15, quad = lane >> 4;
  int wr = wave >> 1, wc = wave & 1;
  int m0 = blockIdx.x * 128, d0 = blockIdx.y * 128;

  int sr = tid >> 2, sc = (tid & 3) * 8;
  const ushort_t* aSrc0 = A  + (long)(m0 + sr) * NN + sc;
  const ushort_t* aSrc1 = aSrc0 + (long)64 * NN;
  const ushort_t* bSrc0 = Bp + (long)(d0 + sr) * NN + sc;
  const ushort_t* bSrc1 = bSrc0 + (long)64 * NN;
  ushort_t* aDst0 = &As[sr * 72 + sc];
  ushort_t* aDst1 = aDst0 + 64 * 72;
  ushort_t* bDst0 = &Bs[sr * 72 + sc];
  ushort_t* bDst1 = bDst0 + 64 * 72;

  {
    uint4 a0 = *(const uint4*)aSrc0;
    uint4 a1 = *(const uint4*)aSrc1;
    uint4 b0 = *(const uint4*)bSrc0;
    uint4 b1 = *(const uint4*)bSrc1;
    *(uint4*)aDst0 = a0; *(uint4*)aDst1 = a1;
    *(uint4*)bDst0 = b0; *(uint4*)bDst1 = b1;
  }
  __syncthreads();

  f32x4 acc[4][4];
  #pragma unroll
  for (int i = 0; i < 4; i++)
    #pragma unroll
    for (int j = 0; j < 4; j++) { acc[i][j][0] = 0.f; acc[i][j][1] = 0.f; acc[i][j][2] = 0.f; acc[i][j][3] = 0.f; }

  for (int ks = 0; ks < 32; ks++) {
    bool more = (ks < 31);
    uint4 na0, na1, nb0, nb1;
    if (more) {
      aSrc0 += 32; aSrc1 += 32; bSrc0 += 32; bSrc1 += 32;
      na0 = *(const uint4*)aSrc0;
      na1 = *(const uint4*)aSrc1;
      nb0 = *(const uint4*)bSrc0;
      nb1 = *(const uint4*)bSrc1;
    }
    short8 af[4], bf[4];
    #pragma unroll
    for (int f = 0; f < 4; f++)
      af[f] = *(const short8*)&As[(wr * 64 + f * 16 + l15) * 72 + quad * 8];
    #pragma unroll
    for (int f = 0; f < 4; f++)
      bf[f] = *(const short8*)&Bs[(wc * 64 + f * 16 + l15) * 72 + quad * 8];
    #pragma unroll
    for (int i = 0; i < 4; i++)
      #pragma unroll
      for (int j = 0; j < 4; j++)
        acc[i][j] = __builtin_amdgcn_mfma_f32_16x16x32_bf16(af[i], bf[j], acc[i][j], 0, 0, 0);
    if (more) {
      __syncthreads();
      *(uint4*)aDst0 = na0;
      *(uint4*)aDst1 = na1;
      *(uint4*)bDst0 = nb0;
      *(uint4*)bDst1 = nb1;
      __syncthreads();
    }
  }

  long xb = ((long)b * LQ + 1) * 256;
  #pragma unroll
  for (int i = 0; i < 4; i++)
    #pragma unroll
    for (int j = 0; j < 4; j++)
      #pragma unroll
      for (int r = 0; r < 4; r++) {
        int m = m0 + wr * 64 + i * 16 + quad * 4 + r;
        int d = d0 + wc * 64 + j * 16 + l15;
        long idx = xb + (long)m * 256 + d;
        X[idx] = acc[i][j][r];
        Xh[idx] = f2b(acc[i][j][r]);
      }
}

// ---------------- attention: single-pass online softmax (deferred rescale) ----------------
// R9-measured version verbatim (67.7 us, 9x-reproduced): single-buffered K/V,
// scalar ls + Lbuf publish + f2b P-packing + balanced pairwise chunk-max tree.
// Rejected variants (ALL measured): MFMA row-sum denominator (R3, 72.5us); inline-asm
// cvt_pk (R6, WRONG on gfx950); max3-style 3-way max nests (R7, 74.9us, serial dep
// chain); K/V double-buffer + packed convert (R10, 70.0us, occupancy 29->24%);
// residual-fused oproj epilogue (R11, +35us); transposed-V gemm epilogue (R16, +6.5us).
// grid (NB*NH, 9); block 256 = 4 waves, 32 q/wave. Q pre-scaled by C1 (in Wt).
// Online max required (layer-1 scores reach +-150 in exp2 domain). Deferred rescale
// (threshold 8 -> p <= 2^8). K/V chunks staged in LDS, reg-staged (T14).
__global__ __launch_bounds__(256) void attn_fa(const ushort_t* __restrict__ Qh,
                                               const ushort_t* __restrict__ Kh,
                                               const ushort_t* __restrict__ VhT,
                                               ushort_t* __restrict__ Oh) {
  __shared__ __align__(16) ushort_t Ps[4][32][72];
  __shared__ __align__(16) ushort_t Kb[64 * 72];   // pitch 72 (144B = 9*16B)
  __shared__ __align__(16) ushort_t Vb[32 * 72];
  __shared__ float Lbuf[4][32];
  int tid = threadIdx.x;
  int wave = tid >> 6, lane = tid & 63;
  int l15 = lane & 15, quad = lane >> 4;
  int b = blockIdx.x >> 3, h = blockIdx.x & 7;
  long hb = ((long)b * LQ) * BD + h * DH;
  long vB = (long)b * BD * KP;
  int hd0 = h * DH;
  int q0 = blockIdx.y * 128 + wave * 32;
  int lq = lane & 48;

  short8 qB[2];
  #pragma unroll
  for (int t = 0; t < 2; t++) {
    int qc = q0 + t * 16 + l15; if (qc > LQ - 1) qc = LQ - 1;
    qB[t] = *(const short8*)&Qh[hb + (long)qc * BD + quad * 8];
  }

  // per-wave staging assignment: 2 segments of 1KB each
  const ushort_t *s0, *s1;
  ushort_t *d0, *d1;
  long stp;
  if (wave < 2) {
    int kt0 = wave * 2, kt1 = kt0 + 1;
    s0 = Kh + hb + (long)(kt0 * 16 + l15) * BD + quad * 8;
    s1 = Kh + hb + (long)(kt1 * 16 + l15) * BD + quad * 8;
    d0 = &Kb[(kt0 * 16 + l15) * 72 + quad * 8];
    d1 = &Kb[(kt1 * 16 + l15) * 72 + quad * 8];
    stp = (long)64 * BD;
  } else {
    int sa = (wave - 2) * 2, sb = sa + 1;   // dt = s>>1, ks = s&1
    s0 = VhT + vB + (long)(hd0 + (sa >> 1) * 16 + l15) * KP + (sa & 1) * 32 + quad * 8;
    s1 = VhT + vB + (long)(hd0 + (sb >> 1) * 16 + l15) * KP + (sb & 1) * 32 + quad * 8;
    d0 = &Vb[((sa >> 1) * 16 + l15) * 72 + (sa & 1) * 32 + quad * 8];
    d1 = &Vb[((sb >> 1) * 16 + l15) * 72 + (sb & 1) * 32 + quad * 8];
    stp = 64;
  }
  {
    uint4 r0 = *(const uint4*)s0;
    uint4 r1 = *(const uint4*)s1;
    *(uint4*)d0 = r0;
    *(uint4*)d1 = r1;
  }
  __syncthreads();

  f32x4 o[2][2];
  #pragma unroll
  for (int t = 0; t < 2; t++)
    #pragma unroll
    for (int dt = 0; dt < 2; dt++) { o[t][dt][0] = 0.f; o[t][dt][1] = 0.f; o[t][dt][2] = 0.f; o[t][dt][3] = 0.f; }
  float m[2] = {-1e30f, -1e30f};
  float ls[2] = {0.f, 0.f};
  f32x4 zf; zf[0] = 0.f; zf[1] = 0.f; zf[2] = 0.f; zf[3] = 0.f;

  for (int c = 0; c < 17; c++) {
    bool more = (c < 16);
    uint4 n0, n1;
    if (more) {
      if (c == 15 && wave < 2) {
        // chunk 16 K rows (1024..1087) all clamp to row 1024; masked in compute
        const ushort_t* cl = Kh + hb + (long)(LQ - 1) * BD + quad * 8;
        n0 = *(const uint4*)cl;
        n1 = n0;
      } else {
        s0 += stp; s1 += stp;
        n0 = *(const uint4*)s0;
        n1 = *(const uint4*)s1;
      }
    }
    short8 ka[4];
    #pragma unroll
    for (int kt = 0; kt < 4; kt++)
      ka[kt] = *(const short8*)&Kb[(kt * 16 + l15) * 72 + quad * 8];

    bool tail = (c == 16);
    #pragma unroll
    for (int t = 0; t < 2; t++) {
      f32x4 s[4];
      #pragma unroll
      for (int kt = 0; kt < 4; kt++)
        s[kt] = __builtin_amdgcn_mfma_f32_16x16x32_bf16(ka[kt], qB[t], zf, 0, 0, 0);
      if (tail) {
        // only key 1024 (kt=0, quad=0, r=0) is valid; mask the rest
        #pragma unroll
        for (int kt = 0; kt < 4; kt++)
          #pragma unroll
          for (int r = 0; r < 4; r++)
            if (kt + r) s[kt][r] = -1e30f;
        if (quad) s[0][0] = -1e30f;
      }
      // chunk row-max (balanced pairwise tree -- max ILP; scores already in exp2 domain)
      float cm = fmaxf(fmaxf(s[0][0], s[0][1]), fmaxf(s[0][2], s[0][3]));
      cm = fmaxf(cm, fmaxf(fmaxf(s[1][0], s[1][1]), fmaxf(s[1][2], s[1][3])));
      cm = fmaxf(cm, fmaxf(fmaxf(s[2][0], s[2][1]), fmaxf(s[2][2], s[2][3])));
      cm = fmaxf(cm, fmaxf(fmaxf(s[3][0], s[3][1]), fmaxf(s[3][2], s[3][3])));
      cm = fmaxf(cm, __shfl_xor(cm, 16));
      cm = fmaxf(cm, __shfl_xor(cm, 32));
      if (__any(cm > m[t] + 8.f)) {
        float mn = fmaxf(m[t], cm);
        float f = fexp2(m[t] - mn);
        ls[t] *= f;
        m[t] = mn;
        #pragma unroll
        for (int r = 0; r < 4; r++) {
          // o-row q = quad*4+r lives at lane l15 = quad*4+r (same quad group)
          float fr = __shfl(f, lq | (quad * 4 + r));
          o[t][0][r] *= fr;
          o[t][1][r] *= fr;
        }
      }
      float mt = m[t];
      #pragma unroll
      for (int kt = 0; kt < 4; kt++) {
        float p0 = fexp2(s[kt][0] - mt);
        float p1 = fexp2(s[kt][1] - mt);
        float p2 = fexp2(s[kt][2] - mt);
        float p3 = fexp2(s[kt][3] - mt);
        ls[t] += (p0 + p1) + (p2 + p3);
        unsigned lo = (unsigned)f2b(p0) | ((unsigned)f2b(p1) << 16);
        unsigned hi = (unsigned)f2b(p2) | ((unsigned)f2b(p3) << 16);
        uint2 w; w.x = lo; w.y = hi;
        *(uint2*)&Ps[wave][t * 16 + l15][kt * 16 + quad * 4] = w;
      }
    }
    // PV: o[q][d] += P[q][keys] * V[keys][d]  (Ps wave-private)
    short8 vb[2][2];
    #pragma unroll
    for (int dt = 0; dt < 2; dt++)
      #pragma unroll
      for (int ks = 0; ks < 2; ks++)
        vb[ks][dt] = *(const short8*)&Vb[(dt * 16 + l15) * 72 + ks * 32 + quad * 8];
    #pragma unroll
    for (int ks = 0; ks < 2; ks++) {
      short8 pa0 = *(const short8*)&Ps[wave][l15][ks * 32 + quad * 8];
      short8 pa1 = *(const short8*)&Ps[wave][16 + l15][ks * 32 + quad * 8];
      #pragma unroll
      for (int dt = 0; dt < 2; dt++) {
        o[0][dt] = __builtin_amdgcn_mfma_f32_16x16x32_bf16(pa0, vb[ks][dt], o[0][dt], 0, 0, 0);
        o[1][dt] = __builtin_amdgcn_mfma_f32_16x16x32_bf16(pa1, vb[ks][dt], o[1][dt], 0, 0, 0);
      }
    }
    if (more) {
      __syncthreads();           // everyone done reading Kb/Vb
      *(uint4*)d0 = n0;          // waits vmcnt via reg dependency
      *(uint4*)d1 = n1;
      __syncthreads();           // chunk c+1 staged
    }
  }
  // denominator: reduce quad-copies, publish via LDS with a full barrier
  #pragma unroll
  for (int t = 0; t < 2; t++) {
    ls[t] += __shfl_xor(ls[t], 16);
    ls[t] += __shfl_xor(ls[t], 32);
  }
  if (quad == 0) {
    Lbuf[wave][l15] = ls[0];
    Lbuf[wave][16 + l15] = ls[1];
  }
  __syncthreads();
  #pragma unroll
  for (int mt = 0; mt < 2; mt++) {
    f32x4 lv = *(const f32x4*)&Lbuf[wave][mt * 16 + quad * 4];
    #pragma unroll
    for (int r = 0; r < 4; r++) {
      int row = q0 + mt * 16 + quad * 4 + r;
      if (row < LQ) {
        float den = lv[r];
        float inv = (den > 0.f) ? 1.f / den : 0.f;
        #pragma unroll
        for (int dt = 0; dt < 2; dt++)
          Oh[hb + (long)row * BD + dt * 16 + l15] = f2b(o[mt][dt][r] * inv);
      }
    }
  }
}

// ---------------- relay attention: Lq=1, Lk=1024, bf16 K/V ----------------
// Barrier-light (R13) + fused q-projection (R15) + uint4 K-row loads (this round:
// 4x16B loads per key instead of 16 scalar dwords; same pairwise accumulation order).
__global__ __launch_bounds__(256) void attn_relay(const float* __restrict__ X, long xstride,
                                                  const float* __restrict__ Wq,
                                                  const ushort_t* __restrict__ K,
                                                  const ushort_t* __restrict__ V,
                                                  float* __restrict__ o) {
  int b = blockIdx.x, h = blockIdx.y;
  int tid = threadIdx.x;
  int wave = tid >> 6, lane = tid & 63;
  const float scale = 0.17677669529663687f;
  __shared__ float s[NN];
  __shared__ float xs[BD];
  __shared__ float qs[DH];
  __shared__ float pmax[4], psum[4];
  __shared__ float part[8][33];
  // --- fused q projection: qs[d] = X[b] . Wq[:, h*DH + d] ---
  xs[tid] = X[(long)b * xstride + tid];
  __syncthreads();
  {
    int d = tid & 31, slice = tid >> 5;
    const float* wq = Wq + h * DH + d;
    float partial = 0.f;
    #pragma unroll
    for (int kk = 0; kk < 32; kk++) {
      int k = slice * 32 + kk;
      partial += xs[k] * wq[(long)k * BD];
    }
    part[slice][d] = partial;
  }
  __syncthreads();
  if (tid < DH) {
    float ss = 0.f;
    #pragma unroll
    for (int t = 0; t < 8; t++) ss += part[t][tid];
    qs[tid] = ss;
  }
  __syncthreads();
  // --- scores (vectorized 16B K loads) ---
  long base = ((long)b * NN) * BD + h * DH;
  float lm = -1e30f;
  for (int k = tid; k < NN; k += 256) {
    const ushort_t* kr = &K[base + (long)k * BD];
    uint4 w0 = *(const uint4*)&kr[0];
    uint4 w1 = *(const uint4*)&kr[8];
    uint4 w2 = *(const uint4*)&kr[16];
    uint4 w3 = *(const uint4*)&kr[24];
    float dot = dot8(w0, &qs[0]) + dot8(w1, &qs[8]);
    dot += dot8(w2, &qs[16]) + dot8(w3, &qs[24]);
    float sv = dot * scale;
    s[k] = sv;
    lm = fmaxf(lm, sv);
  }
  lm = wave_max(lm);
  if (lane == 0) pmax[wave] = lm;
  __syncthreads();          // s[] visible + pmax visible
  float mx = fmaxf(fmaxf(pmax[0], pmax[1]), fmaxf(pmax[2], pmax[3]));
  float sm = 0.f;
  for (int k = tid; k < NN; k += 256) {
    float p = __expf(s[k] - mx);
    s[k] = p;
    sm += p;
  }
  sm = wave_sum(sm);
  if (lane == 0) psum[wave] = sm;
  __syncthreads();          // exp'd s[] visible + psum visible
  float inv = 1.f / (((psum[0] + psum[1]) + (psum[2] + psum[3])));
  int d = tid & 31, slice = tid >> 5;
  float acc = 0.f;
  for (int k = slice; k < NN; k += 8) acc += s[k] * b2f(V[base + (long)k * BD + d]);
  part[slice][d] = acc;
  __syncthreads();
  if (tid < DH) {
    float ss = 0.f;
    #pragma unroll
    for (int t = 0; t < 8; t++) ss += part[t][tid];
    o[(long)b * BD + h * DH + tid] = ss * inv;
  }
}

// ---------------- relay row ops (fp32 weights; tiny) ----------------
__global__ __launch_bounds__(256) void rowvec_oproj_ln(const float* __restrict__ o,
                                                       const float* __restrict__ Wo,
                                                       const float* __restrict__ Xres, long xstride,
                                                       const float* __restrict__ g,
                                                       const float* __restrict__ beta,
                                                       float* __restrict__ dst, long dstride,
                                                       ushort_t* __restrict__ dsth, long dhstride) {
  int b = blockIdx.x, tid = threadIdx.x;
  int wave = tid >> 6, lane = tid & 63;
  __shared__ float xs[BD];
  __shared__ float ps[4], pq[4];
  xs[tid] = o[(long)b * BD + tid];
  __syncthreads();
  float acc = 0.f;
  for (int k = 0; k < BD; k++) acc += xs[k] * Wo[(long)k * BD + tid];
  float v = acc + Xres[(long)b * xstride + tid];
  float sum = wave_sum(v);
  float sq  = wave_sum(v * v);
  if (lane == 0) { ps[wave] = sum; pq[wave] = sq; }
  __syncthreads();
  float ts = (ps[0] + ps[1]) + (ps[2] + ps[3]);
  float tq = (pq[0] + pq[1]) + (pq[2] + pq[3]);
  float mu = ts * (1.f / BD);
  float var = tq * (1.f / BD) - mu * mu;
  float y = (v - mu) * rsqrtf(var + EPSV) * g[tid] + beta[tid];
  dst[(long)b * dstride + tid] = y;
  if (dsth) dsth[(long)b * dhstride + tid] = f2b(y);
}

// ln_residual with optional fused sat-output store (replaces k_sat_out at layer 2):
// sat_out[b][r-1][:] = y for sat rows r>=1. Wave-shfl reduction: 1 barrier (was 9).
// When sat_out is set (layer 2), X sat-row writes are DEAD (only relay rows of X
// are read after layer 2; sat output flows through sat_out) -- skip them.
__global__ __launch_bounds__(256) void ln_residual(const float* __restrict__ OP,
                                                   float* __restrict__ X,
                                                   ushort_t* __restrict__ Xh,
                                                   const float* __restrict__ g,
                                                   const float* __restrict__ beta,
                                                   float* __restrict__ sat_out) {
  long r = blockIdx.x;
  int tid = threadIdx.x;
  int wave = tid >> 6, lane = tid & 63;
  __shared__ float ps[4], pq[4];
  float v = OP[r * BD + tid] + X[r * BD + tid];
  float sum = wave_sum(v);
  float sq  = wave_sum(v * v);
  if (lane == 0) { ps[wave] = sum; pq[wave] = sq; }
  __syncthreads();
  float ts = (ps[0] + ps[1]) + (ps[2] + ps[3]);
  float tq = (pq[0] + pq[1]) + (pq[2] + pq[3]);
  float mu = ts * (1.f / BD);
  float var = tq * (1.f / BD) - mu * mu;
  float y = (v - mu) * rsqrtf(var + EPSV) * g[tid] + beta[tid];
  Xh[r * BD + tid] = f2b(y);
  if (sat_out) {
    long b = r / LQ;
    long rr = r - b * LQ;
    if (rr > 0)
      sat_out[(b * (long)NN + (rr - 1)) * BD + tid] = y;
    else
      X[r * BD + tid] = y;       // relay row still needed by layer 3
  } else {
    X[r * BD + tid] = y;
  }
}

// ---------------- launch ----------------
extern "C" void kernel_launch(void* const* d_in, const int* in_sizes, int n_in,
                              void* d_out, int out_size, void* d_ws, size_t ws_size,
                              hipStream_t stream) {
  const float* gv    = (const float*)d_in[0];
  const float* graph = (const float*)d_in[1];
  const float* Wq    = (const float*)d_in[2];
  const float* Wk    = (const float*)d_in[3];
  const float* Wv    = (const float*)d_in[4];
  const float* Wo    = (const float*)d_in[5];
  const float* lg    = (const float*)d_in[6];
  const float* lb    = (const float*)d_in[7];
  float* out = (float*)d_out;

  const long S  = (long)NB * LQ * BD;   // 4,198,400
  const long S4 = S * 4, S2 = S * 2;
  char* base = (char*)d_ws;
  // layout: X(S4), Xh(S2), B1(S4), Qh(S2), Kh(S2), Vh(S2), Oh(S2), Wt(2MB), orel.
  // aliases (time-shared): Ght = B1..Kh (32MB, pre-layer1 only); satT = Vh (pre-layer1);
  // VhT = B1[0..8.9MB] during self layers (B1 dead until oproj).
  float*    X    = (float*)base;
  ushort_t* Xh   = (ushort_t*)(base + S4);
  float*    B1   = (float*)(base + S4 + S2);
  ushort_t* Qh   = (ushort_t*)(base + 2 * S4 + S2);
  ushort_t* Kh   = (ushort_t*)(base + 2 * S4 + 2 * S2);
  ushort_t* Vh   = (ushort_t*)(base + 2 * S4 + 3 * S2);
  ushort_t* Oh   = (ushort_t*)(base + 2 * S4 + 4 * S2);
  ushort_t* Wt   = (ushort_t*)(base + 2 * S4 + 5 * S2);
  float*    orel = (float*)(base + 2 * S4 + 5 * S2 + 16L * 65536 * 2);
  ushort_t* Ght  = (ushort_t*)B1;
  ushort_t* satT = Vh;
  ushort_t* VhT  = (ushort_t*)B1;

  const long WSZ = (long)BD * BD;
  const long XST = (long)LQ * BD;
  dim3 blk(256);

  k_copy_cast<<<dim3(2048), blk, 0, stream>>>(gv, X, Xh, S);
  k_wtrans<<<dim3(64, 16), blk, 0, stream>>>(Wq, Wk, Wv, Wo, Wt);

  // ---- layer 0: relay GAT (q-projection fused into attn_relay) ----
  gemm_kv<<<dim3(8, 4, NB), blk, 0, stream>>>(Xh, Wt, 0, Kh, Vh);
  attn_relay<<<dim3(NB, NH), blk, 0, stream>>>(X, XST, Wq + 0 * WSZ, Kh, Vh, orel);
  rowvec_oproj_ln<<<dim3(NB), blk, 0, stream>>>(orel, Wo + 0 * WSZ, X, XST,
                                                lg + 0 * BD, lb + 0 * BD, X, XST, Xh, XST);

  // ---- sat mixing: sat = G^T @ sat (pre-transposed MFMA) ----
  k_gtrans<<<dim3(256, NB), blk, 0, stream>>>(graph, Ght);
  k_satT<<<dim3(64, NB), blk, 0, stream>>>(Xh, satT);
  gemm_gtx2<<<dim3(8, 2, NB), blk, 0, stream>>>(Ght, satT, X, Xh);

  // ---- layers 1,2: self GAT (layer 2's ln_residual also emits sat_u) ----
  for (int l = 1; l <= 2; l++) {
    gemm_qkv<<<dim3(129, 6), blk, 0, stream>>>(Xh, Wt, l, Qh, Kh, Vh, NB * LQ);
    k_vtrans<<<dim3(17, 4, NB), blk, 0, stream>>>(Vh, VhT);
    attn_fa<<<dim3(NB * NH, 9), blk, 0, stream>>>(Qh, Kh, VhT, Oh);
    gemm_oproj<<<dim3(129, 2), blk, 0, stream>>>(Oh, Wt, l, B1, NB * LQ);
    ln_residual<<<dim3(NB * LQ), blk, 0, stream>>>(B1, X, Xh, lg + l * BD, lb + l * BD,
                                                   (l == 2) ? (out + (long)NB * BD) : nullptr);
  }

  // ---- layer 3: final relay GAT -> z (q-projection fused into attn_relay) ----
  gemm_kv<<<dim3(8, 4, NB), blk, 0, stream>>>(Xh, Wt, 3, Kh, Vh);
  attn_relay<<<dim3(NB, NH), blk, 0, stream>>>(X, XST, Wq + 3 * WSZ, Kh, Vh, orel);
  rowvec_oproj_ln<<<dim3(NB), blk, 0, stream>>>(orel, Wo + 3 * WSZ, X, XST,
                                                lg + 3 * BD, lb + 3 * BD, out, BD, nullptr, 0);
}